// Round 13
// baseline (2831.486 us; speedup 1.0000x reference)
//
#include <hip/hip_runtime.h>
#include <math.h>

// ---------------- problem constants ----------------
#define NTOK  65536
#define EDIM  128
#define HN    4
#define DHD   32
#define MF    256
#define LLAYERS 2
#define INDIM 512
#define FDIM  512
#define CR    512
#define NCHK  (NTOK/CR)

#define DN    0.4204482076268573f
#define DN2   0.17677669529663687f
#define KEPS  1e-4f

typedef unsigned short u16;
typedef unsigned int   u32;
typedef __attribute__((ext_vector_type(8))) __bf16 bf16x8;
typedef __attribute__((ext_vector_type(4))) float  f32x4;

__device__ __forceinline__ u16 f2bf(float f){
  u32 u = __float_as_uint(f);
  u32 r = (u + 0x7fffu + ((u >> 16) & 1u)) >> 16;   // RNE
  return (u16)r;
}
__device__ __forceinline__ float bf2f(u16 h){ return __uint_as_float(((u32)h) << 16); }

__device__ __forceinline__ void gload_lds16(const void* g, void* l){
  __builtin_amdgcn_global_load_lds(
      (const __attribute__((address_space(1))) u32*)g,
      (__attribute__((address_space(3))) u32*)l, 16, 0, 0);
}

// ---------------- prep ----------------
struct PrepArgs {
  const float* Wpin; const float* Wq; const float* Wk; const float* Wv;
  const float* Wo;   const float* Wpo; const float* Wf1; const float* Wf2;
  const float* Wn1;  const float* Wn2; const float* proj;
};

__global__ __launch_bounds__(256) void prep_kernel(PrepArgs a, u16* __restrict__ wts,
                                                   u16* __restrict__ pjb)
{
  int idx = blockIdx.x * 256 + threadIdx.x;
  const float* sp; u16* dp; int r, K, J;
  if      (idx <  65536) { sp = a.Wpin; dp = wts;          r = idx;          K = 512; J = 128; }
  else if (idx <  98304) { sp = a.Wq;   dp = wts +  65536; r = idx -  65536; K = 128; J = 128; }
  else if (idx < 131072) { sp = a.Wk;   dp = wts +  98304; r = idx -  98304; K = 128; J = 128; }
  else if (idx < 163840) { sp = a.Wv;   dp = wts + 131072; r = idx - 131072; K = 128; J = 128; }
  else if (idx < 196608) { sp = a.Wo;   dp = wts + 163840; r = idx - 163840; K = 128; J = 128; }
  else if (idx < 229376) { sp = a.Wpo;  dp = wts + 196608; r = idx - 196608; K = 128; J = 128; }
  else if (idx < 360448) { sp = a.Wf1;  dp = wts + 229376; r = idx - 229376; K = 128; J = 512; }
  else if (idx < 491520) { sp = a.Wf2;  dp = wts + 360448; r = idx - 360448; K = 512; J = 128; }
  else if (idx < 622592) { sp = a.Wn1;  dp = wts + 491520; r = idx - 491520; K = 128; J = 512; }
  else if (idx < 753664) { sp = a.Wn2;  dp = wts + 622592; r = idx - 622592; K = 512; J = 128; }
  else { int p = idx - 753664; pjb[p] = f2bf(a.proj[p] * DN); return; }
  int kj = K * J;
  int l = r / kj, rr = r - l * kj;
  int j = rr / K, k = rr - j * K;
  dp[r] = f2bf(sp[(size_t)l * kj + (size_t)k * J + j]);
}

// ---------------- input GEMM: h = x@Wpin + b (fp32 A), y = LN(h) ----------------
__global__ __launch_bounds__(256, 4) void gemm_in(
    const float* __restrict__ Af, const u16* __restrict__ Bt,
    const float* __restrict__ bias,
    u16* __restrict__ outRaw,
    const float* __restrict__ g1, const float* __restrict__ b1, u16* __restrict__ outL1)
{
  __shared__ __align__(16) u16 Al[3][2048];
  __shared__ __align__(16) u16 Bl[3][4096];
  __shared__ float lnred[2][2][32][2];
  const int tid  = threadIdx.x;
  const int lane = tid & 63;
  const int w    = tid >> 6;
  const int wr   = w >> 1, wc = w & 1;
  const int bid  = blockIdx.x;
  const int bsw  = (bid & 7) * (gridDim.x >> 3) + (bid >> 3);
  const int n0   = bsw * 64;

  f32x4 acc[2][4];
#pragma unroll
  for (int m = 0; m < 2; ++m)
#pragma unroll
    for (int n = 0; n < 4; ++n) acc[m][n] = (f32x4){0.f, 0.f, 0.f, 0.f};

  const int srow = lane >> 2;
  const int skg  = (lane & 3) ^ ((lane >> 3) & 3);

  auto stageB = [&](int buf, int k0) {
#pragma unroll
    for (int i = 0; i < 2; ++i) {
      const int rb = 2 * w + i;
      gload_lds16(Bt + (size_t)(rb * 16 + srow) * 512 + k0 + skg * 8,
                  &Bl[buf][rb * 512]);
    }
  };

  const int r16f = lane & 15;
  const int kgl  = (lane >> 4) ^ ((lane >> 1) & 3);
  const int foff = r16f * 32 + kgl * 8;

  constexpr int T = 16;
  float4 fA[3][2];
  const int r = tid >> 2, hf = tid & 3;
  auto loadA = [&](int slot, int k0) {
    const float* gp = Af + (size_t)(n0 + r) * 512 + k0 + hf * 8;
    fA[slot][0] = ((const float4*)gp)[0];
    fA[slot][1] = ((const float4*)gp)[1];
  };
  const int rbA = r >> 4, r16A = r & 15, swzA = (r16A >> 1) & 3;
  auto writeA = [&](int slot, int buf) {
    uint4 p0;
    p0.x = (u32)f2bf(fA[slot][0].x) | ((u32)f2bf(fA[slot][0].y) << 16);
    p0.y = (u32)f2bf(fA[slot][0].z) | ((u32)f2bf(fA[slot][0].w) << 16);
    p0.z = (u32)f2bf(fA[slot][1].x) | ((u32)f2bf(fA[slot][1].y) << 16);
    p0.w = (u32)f2bf(fA[slot][1].z) | ((u32)f2bf(fA[slot][1].w) << 16);
    *reinterpret_cast<uint4*>(&Al[buf][rbA * 512 + r16A * 32 + (hf ^ swzA) * 8]) = p0;
  };
  loadA(0, 0); loadA(1, 32); loadA(2, 64);
  stageB(0, 0); stageB(1, 32);
  asm volatile("s_waitcnt vmcnt(8)" ::: "memory");
  writeA(0, 0);
#pragma unroll
  for (int t = 0; t < T; ++t) {
    if (t + 2 < T) asm volatile("s_waitcnt vmcnt(4) lgkmcnt(0)" ::: "memory");
    else           asm volatile("s_waitcnt vmcnt(0) lgkmcnt(0)" ::: "memory");
    __builtin_amdgcn_s_barrier();
    if (t + 1 < T) writeA((t + 1) % 3, (t + 1) % 3);
    if (t + 3 < T) loadA((t + 3) % 3, (t + 3) * 32);
    if (t + 2 < T) stageB((t + 2) % 3, (t + 2) * 32);
    {
      const int cur = t % 3;
      bf16x8 af[2], bfg[4];
#pragma unroll
      for (int m = 0; m < 2; ++m)
        af[m]  = *reinterpret_cast<const bf16x8*>(&Al[cur][(wr * 2 + m) * 512 + foff]);
#pragma unroll
      for (int n = 0; n < 4; ++n)
        bfg[n] = *reinterpret_cast<const bf16x8*>(&Bl[cur][(wc * 4 + n) * 512 + foff]);
#pragma unroll
      for (int m = 0; m < 2; ++m)
#pragma unroll
        for (int n = 0; n < 4; ++n)
          acc[m][n] = __builtin_amdgcn_mfma_f32_16x16x32_bf16(af[m], bfg[n], acc[m][n], 0, 0, 0);
    }
  }
  __builtin_amdgcn_s_barrier();

  const int colb = wc * 64 + (lane & 15);
  const int rowb = n0 + wr * 32 + (lane >> 4) * 4;
  float bv[4];
#pragma unroll
  for (int n = 0; n < 4; ++n) bv[n] = bias[colb + n * 16];

  float v[2][4][4];
#pragma unroll
  for (int m = 0; m < 2; ++m)
#pragma unroll
    for (int n = 0; n < 4; ++n)
#pragma unroll
      for (int j = 0; j < 4; ++j)
        v[m][n][j] = acc[m][n][j] + bv[n];

#pragma unroll
  for (int m = 0; m < 2; ++m)
#pragma unroll
    for (int n = 0; n < 4; ++n)
#pragma unroll
      for (int j = 0; j < 4; ++j)
        outRaw[(size_t)(rowb + m * 16 + j) * EDIM + colb + n * 16] = f2bf(v[m][n][j]);

  float rs[2][4], rq[2][4];
#pragma unroll
  for (int m = 0; m < 2; ++m)
#pragma unroll
    for (int j = 0; j < 4; ++j) {
      float s = 0.f, q = 0.f;
#pragma unroll
      for (int n = 0; n < 4; ++n) { float t = v[m][n][j]; s += t; q += t * t; }
      rs[m][j] = s; rq[m][j] = q;
    }
#pragma unroll
  for (int o = 1; o < 16; o <<= 1)
#pragma unroll
    for (int m = 0; m < 2; ++m)
#pragma unroll
      for (int j = 0; j < 4; ++j) {
        rs[m][j] += __shfl_xor(rs[m][j], o);
        rq[m][j] += __shfl_xor(rq[m][j], o);
      }
  __syncthreads();
  if ((lane & 15) == 0) {
#pragma unroll
    for (int m = 0; m < 2; ++m)
#pragma unroll
      for (int j = 0; j < 4; ++j) {
        int rloc = m * 16 + (lane >> 4) * 4 + j;
        lnred[wr][wc][rloc][0] = rs[m][j];
        lnred[wr][wc][rloc][1] = rq[m][j];
      }
  }
  __syncthreads();
  float gg[4], bb[4];
#pragma unroll
  for (int n = 0; n < 4; ++n) { gg[n] = g1[colb + n * 16]; bb[n] = b1[colb + n * 16]; }
#pragma unroll
  for (int m = 0; m < 2; ++m)
#pragma unroll
    for (int j = 0; j < 4; ++j) {
      int rloc = m * 16 + (lane >> 4) * 4 + j;
      float ts = rs[m][j] + lnred[wr][wc ^ 1][rloc][0];
      float tq = rq[m][j] + lnred[wr][wc ^ 1][rloc][1];
      float mu = ts * (1.f / 128.f);
      float rsig = rsqrtf(tq * (1.f / 128.f) - mu * mu + 1e-5f);
#pragma unroll
      for (int n = 0; n < 4; ++n)
        outL1[(size_t)(rowb + m * 16 + j) * EDIM + colb + n * 16] =
            f2bf((v[m][n][j] - mu) * rsig * gg[n] + bb[n]);
    }
}

// ---------------- QKV fused: resident-A, 12 weight stages (q,k,v x 4), 4-deep ----------
__global__ __launch_bounds__(256, 3) void qkv_f(
    const u16* __restrict__ A0, const u16* __restrict__ Wt,
    u16* __restrict__ qout, u16* __restrict__ kout, u16* __restrict__ vtout)
{
  __shared__ __align__(16) u16 As[4][2048];
  __shared__ __align__(16) u16 Bs[4][4096];
  const int tid  = threadIdx.x;
  const int lane = tid & 63;
  const int w    = tid >> 6;
  const int wr   = w >> 1, wc = w & 1;
  const int bid  = blockIdx.x;
  const int bsw  = (bid & 7) * (gridDim.x >> 3) + (bid >> 3);
  const int n0   = bsw * 64;

  const int srow = lane >> 2;
  const int skg  = (lane & 3) ^ ((lane >> 3) & 3);
  const int r16f = lane & 15;
  const int kgl  = (lane >> 4) ^ ((lane >> 1) & 3);
  const int foff = r16f * 32 + kgl * 8;
  const int colb = wc * 64 + (lane & 15);
  const int rowb = n0 + wr * 32 + (lane >> 4) * 4;

#pragma unroll
  for (int rb = 0; rb < 4; ++rb)
    gload_lds16(A0 + (size_t)(n0 + rb * 16 + srow) * EDIM + w * 32 + skg * 8, &As[w][rb * 512]);

  auto stageB = [&](int buf, int st) {
    const u16* base = Wt + (size_t)(st >> 2) * 32768;
    const int kb0 = (st & 3) * 32;
#pragma unroll
    for (int i = 0; i < 2; ++i) {
      const int rb = 2 * w + i;
      gload_lds16(base + (size_t)(rb * 16 + srow) * 128 + kb0 + skg * 8, &Bs[buf][rb * 512]);
    }
  };
  stageB(0, 0); stageB(1, 1); stageB(2, 2);

  f32x4 acc[2][4];
  float v[2][4][4];

#pragma unroll
  for (int st = 0; st < 12; ++st) {
    if (st < 10)       asm volatile("s_waitcnt vmcnt(4) lgkmcnt(0)" ::: "memory");
    else if (st == 10) asm volatile("s_waitcnt vmcnt(2) lgkmcnt(0)" ::: "memory");
    else               asm volatile("s_waitcnt vmcnt(0) lgkmcnt(0)" ::: "memory");
    __builtin_amdgcn_s_barrier();
    if (st + 3 < 12) stageB((st + 3) & 3, st + 3);
    if ((st & 3) == 0) {
#pragma unroll
      for (int m = 0; m < 2; ++m)
#pragma unroll
        for (int n = 0; n < 4; ++n) acc[m][n] = (f32x4){0.f, 0.f, 0.f, 0.f};
    }
    const int kt = st & 3;
    bf16x8 af[2], bfg[4];
#pragma unroll
    for (int m = 0; m < 2; ++m)
      af[m]  = *reinterpret_cast<const bf16x8*>(&As[kt][(wr * 2 + m) * 512 + foff]);
#pragma unroll
    for (int n = 0; n < 4; ++n)
      bfg[n] = *reinterpret_cast<const bf16x8*>(&Bs[st & 3][(wc * 4 + n) * 512 + foff]);
#pragma unroll
    for (int m = 0; m < 2; ++m)
#pragma unroll
      for (int n = 0; n < 4; ++n)
        acc[m][n] = __builtin_amdgcn_mfma_f32_16x16x32_bf16(af[m], bfg[n], acc[m][n], 0, 0, 0);
    if (st == 3 || st == 7) {
      u16* out = (st == 3) ? qout : kout;
#pragma unroll
      for (int m = 0; m < 2; ++m)
#pragma unroll
        for (int n = 0; n < 4; ++n)
#pragma unroll
          for (int j = 0; j < 4; ++j)
            out[(size_t)(rowb + m * 16 + j) * EDIM + colb + n * 16] = f2bf(acc[m][n][j]);
    }
    if (st == 11) {
#pragma unroll
      for (int m = 0; m < 2; ++m)
#pragma unroll
        for (int n = 0; n < 4; ++n)
#pragma unroll
          for (int j = 0; j < 4; ++j) v[m][n][j] = acc[m][n][j];
    }
  }

  __syncthreads();
  u16* tb = &Bs[0][0];   // 128*72*2 = 18KB < 32KB
#pragma unroll
  for (int m = 0; m < 2; ++m)
#pragma unroll
    for (int n = 0; n < 4; ++n)
#pragma unroll
      for (int j = 0; j < 4; ++j)
        tb[(wc * 64 + n * 16 + (lane & 15)) * 72 + wr * 32 + m * 16 + (lane >> 4) * 4 + j]
            = f2bf(v[m][n][j]);
  __syncthreads();
  { const int c2 = tid >> 1, hf2 = tid & 1;
    const uint4* src = reinterpret_cast<const uint4*>(&tb[c2 * 72 + hf2 * 32]);
    uint4* dst = reinterpret_cast<uint4*>(vtout + (size_t)c2 * NTOK + n0 + hf2 * 32);
    dst[0] = src[0]; dst[1] = src[1]; dst[2] = src[2]; dst[3] = src[3]; }
}

// ---------------- MEGA12: full attn-out + both FFN chains for one layer ----------------
// Phase A (st 0-35):  h1 = hb + a@Wo + bo;  y2 = LN_lb(h1) -> As;  h2 = h1 + gelu(y2@Wf1+bf1)@Wf2+bf2
// Phase B (st 36-71): h' = LN_n1(hb + h2@Wpo + bpo) -> As;  h = LN_n2(h' + relu(h'@Wn1+bn1)@Wn2+bn2)
// Tail: LNM==2 -> out=h(hb), outL2=LN_lag(h)(yb); LNM==3 -> out=h, classifier -> outCls.
template<int LNM>
__global__ __launch_bounds__(256, 2) void mega12(
    const u16* __restrict__ A0, const u16* __restrict__ hbuf,
    const u16* __restrict__ W0a, const float* __restrict__ b0a,
    const float* __restrict__ gA, const float* __restrict__ bA,
    const u16* __restrict__ W1a, const float* __restrict__ fb1a,
    const u16* __restrict__ W2a, const float* __restrict__ fb2a,
    const u16* __restrict__ W0b, const float* __restrict__ b0b,
    const float* __restrict__ gB, const float* __restrict__ bB,
    const u16* __restrict__ W1b, const float* __restrict__ fb1b,
    const u16* __restrict__ W2b, const float* __restrict__ fb2b,
    const float* __restrict__ gC, const float* __restrict__ bC,
    u16* __restrict__ out,
    u16* __restrict__ outL2, const float* __restrict__ gD, const float* __restrict__ bD,
    const float* __restrict__ Wcp, const float* __restrict__ bcp, float* __restrict__ outCls)
{
  __shared__ __align__(16) u16 As[4][2048];
  __shared__ __align__(16) u16 Hs[4][2048];
  __shared__ __align__(16) u16 Bs[4][4096];
  __shared__ float lnred[2][2][32][2];
  const int tid  = threadIdx.x;
  const int lane = tid & 63;
  const int w    = tid >> 6;
  const int wr   = w >> 1, wc = w & 1;
  const int bid  = blockIdx.x;
  const int bsw  = (bid & 7) * (gridDim.x >> 3) + (bid >> 3);
  const int n0   = bsw * 64;

  const int srow = lane >> 2;
  const int skg  = (lane & 3) ^ ((lane >> 3) & 3);
  const int r16f = lane & 15;
  const int kgl  = (lane >> 4) ^ ((lane >> 1) & 3);
  const int foff = r16f * 32 + kgl * 8;
  const int colb = wc * 64 + (lane & 15);
  const int rowb = n0 + wr * 32 + (lane >> 4) * 4;

#pragma unroll
  for (int rb = 0; rb < 4; ++rb)
    gload_lds16(A0 + (size_t)(n0 + rb * 16 + srow) * EDIM + w * 32 + skg * 8, &As[w][rb * 512]);

  auto stageB = [&](int buf, int st) {
    const u16* base; size_t rstride; int kb0;
    if (st < 4)       { base = W0a; rstride = 128; kb0 = st * 32; }
    else if (st < 36) {
      int s2 = st - 4;
      int c = s2 >> 3, p = (s2 >> 2) & 1, kt = s2 & 3;
      if (p == 0) { base = W1a + (size_t)c * 16384; rstride = 128; kb0 = kt * 32; }
      else        { base = W2a;                      rstride = 512; kb0 = c * 128 + kt * 32; }
    }
    else if (st < 40) { base = W0b; rstride = 128; kb0 = (st - 36) * 32; }
    else {
      int s2 = st - 40;
      int c = s2 >> 3, p = (s2 >> 2) & 1, kt = s2 & 3;
      if (p == 0) { base = W1b + (size_t)c * 16384; rstride = 128; kb0 = kt * 32; }
      else        { base = W2b;                      rstride = 512; kb0 = c * 128 + kt * 32; }
    }
#pragma unroll
    for (int i = 0; i < 2; ++i) {
      const int rb = 2 * w + i;
      gload_lds16(base + (size_t)(rb * 16 + srow) * rstride + kb0 + skg * 8, &Bs[buf][rb * 512]);
    }
  };

  stageB(0, 0); stageB(1, 1); stageB(2, 2);

  f32x4 acc0[2][4], acc1[2][4], acc2[2][4];
#pragma unroll
  for (int m = 0; m < 2; ++m)
#pragma unroll
    for (int n = 0; n < 4; ++n) { acc0[m][n] = (f32x4){0.f,0.f,0.f,0.f}; acc2[m][n] = (f32x4){0.f,0.f,0.f,0.f}; }

  float v0[2][4][4];

  // shared LN helper over register tile t[2][4][4] (updates in place, fp32)
  auto ln_tile = [&](float (&t)[2][4][4], const float* gp, const float* bp) {
    float rs[2][4], rq[2][4];
#pragma unroll
    for (int m = 0; m < 2; ++m)
#pragma unroll
      for (int j = 0; j < 4; ++j) {
        float s = 0.f, q = 0.f;
#pragma unroll
        for (int n = 0; n < 4; ++n) { float u = t[m][n][j]; s += u; q += u * u; }
        rs[m][j] = s; rq[m][j] = q;
      }
#pragma unroll
    for (int o = 1; o < 16; o <<= 1)
#pragma unroll
      for (int m = 0; m < 2; ++m)
#pragma unroll
        for (int j = 0; j < 4; ++j) {
          rs[m][j] += __shfl_xor(rs[m][j], o);
          rq[m][j] += __shfl_xor(rq[m][j], o);
        }
    __syncthreads();
    if ((lane & 15) == 0) {
#pragma unroll
      for (int m = 0; m < 2; ++m)
#pragma unroll
        for (int j = 0; j < 4; ++j) {
          int rloc = m * 16 + (lane >> 4) * 4 + j;
          lnred[wr][wc][rloc][0] = rs[m][j];
          lnred[wr][wc][rloc][1] = rq[m][j];
        }
    }
    __syncthreads();
    float gg[4], bb[4];
#pragma unroll
    for (int n = 0; n < 4; ++n) { gg[n] = gp[colb + n * 16]; bb[n] = bp[colb + n * 16]; }
#pragma unroll
    for (int m = 0; m < 2; ++m)
#pragma unroll
      for (int j = 0; j < 4; ++j) {
        int rloc = m * 16 + (lane >> 4) * 4 + j;
        float ts = rs[m][j] + lnred[wr][wc ^ 1][rloc][0];
        float tq = rq[m][j] + lnred[wr][wc ^ 1][rloc][1];
        float mu = ts * (1.f / 128.f);
        float rsig = rsqrtf(tq * (1.f / 128.f) - mu * mu + 1e-5f);
#pragma unroll
        for (int n = 0; n < 4; ++n)
          t[m][n][j] = (t[m][n][j] - mu) * rsig * gg[n] + bb[n];
      }
  };
  // write register tile to As in A-operand (swizzled) layout
  auto write_As = [&](const float (&t)[2][4][4]) {
#pragma unroll
    for (int m = 0; m < 2; ++m)
#pragma unroll
      for (int j = 0; j < 4; ++j) {
        const int r16 = (lane >> 4) * 4 + j;
        const int rb  = wr * 2 + m;
#pragma unroll
        for (int n = 0; n < 4; ++n) {
          const int q = wc * 64 + n * 16 + (lane & 15);
          const int ts2 = q >> 5, ql = q & 31;
          const int s = (ql >> 3) ^ ((r16 >> 1) & 3);
          As[ts2][rb * 512 + r16 * 32 + s * 8 + (ql & 7)] = f2bf(t[m][n][j]);
        }
      }
  };

#pragma unroll 1
  for (int st = 0; st < 72; ++st) {
    if (st < 70)       asm volatile("s_waitcnt vmcnt(4) lgkmcnt(0)" ::: "memory");
    else if (st == 70) asm volatile("s_waitcnt vmcnt(2) lgkmcnt(0)" ::: "memory");
    else               asm volatile("s_waitcnt vmcnt(0) lgkmcnt(0)" ::: "memory");
    __builtin_amdgcn_s_barrier();
    if (st + 3 < 72) stageB((st + 3) & 3, st + 3);

    const bool g0phase = (st < 4) || (st >= 36 && st < 40);
    if (g0phase) {
      const int kt = (st < 4) ? st : (st - 36);
      const u16* Bc = &Bs[st & 3][0];
      bf16x8 af[2], bfg[4];
#pragma unroll
      for (int m = 0; m < 2; ++m) af[m]  = *reinterpret_cast<const bf16x8*>(&As[kt][(wr * 2 + m) * 512 + foff]);
#pragma unroll
      for (int n = 0; n < 4; ++n) bfg[n] = *reinterpret_cast<const bf16x8*>(&Bc[(wc * 4 + n) * 512 + foff]);
#pragma unroll
      for (int m = 0; m < 2; ++m)
#pragma unroll
        for (int n = 0; n < 4; ++n)
          acc0[m][n] = __builtin_amdgcn_mfma_f32_16x16x32_bf16(af[m], bfg[n], acc0[m][n], 0, 0, 0);
      if (st == 3) {
        // phase-A GEMM0 epilogue: h1 = acc0 + b0a + hb; y2 = LN_lb(h1) -> As; v0 = h1
        float bv0[4];
#pragma unroll
        for (int n = 0; n < 4; ++n) bv0[n] = b0a[colb + n * 16];
        float t[2][4][4];
#pragma unroll
        for (int m = 0; m < 2; ++m)
#pragma unroll
          for (int n = 0; n < 4; ++n)
#pragma unroll
            for (int j = 0; j < 4; ++j) {
              float h1 = acc0[m][n][j] + bv0[n]
                  + bf2f(hbuf[(size_t)(rowb + m * 16 + j) * EDIM + colb + n * 16]);
              v0[m][n][j] = h1;
              t[m][n][j] = h1;
            }
        ln_tile(t, gA, bA);          // contains syncthreads -> As reads all done
        write_As(t);
      }
      if (st == 39) {
        // phase-B GEMM0 epilogue: hB = acc0 + b0b + hb; h' = LN_n1(hB) -> As; v0 = h'
        float bv0[4];
#pragma unroll
        for (int n = 0; n < 4; ++n) bv0[n] = b0b[colb + n * 16];
        float t[2][4][4];
#pragma unroll
        for (int m = 0; m < 2; ++m)
#pragma unroll
          for (int n = 0; n < 4; ++n)
#pragma unroll
            for (int j = 0; j < 4; ++j)
              t[m][n][j] = acc0[m][n][j] + bv0[n]
                  + bf2f(hbuf[(size_t)(rowb + m * 16 + j) * EDIM + colb + n * 16]);
        ln_tile(t, gB, bB);          // syncthreads inside -> As reads all done
        write_As(t);
#pragma unroll
        for (int m = 0; m < 2; ++m)
#pragma unroll
          for (int n = 0; n < 4; ++n)
#pragma unroll
            for (int j = 0; j < 4; ++j) v0[m][n][j] = t[m][n][j];   // post-LN residual
      }
    } else {
      const bool phA = (st < 36);
      const int s2 = phA ? (st - 4) : (st - 40);
      const int c = s2 >> 3, p = (s2 >> 2) & 1, kt = s2 & 3;
      if ((s2 & 7) == 0) {
#pragma unroll
        for (int m = 0; m < 2; ++m)
#pragma unroll
          for (int n = 0; n < 4; ++n) acc1[m][n] = (f32x4){0.f, 0.f, 0.f, 0.f};
      }
      const u16* Asrc = p ? &Hs[kt][0] : &As[kt][0];
      const u16* Bc = &Bs[st & 3][0];
      bf16x8 af[2], bfg[4];
#pragma unroll
      for (int m = 0; m < 2; ++m) af[m]  = *reinterpret_cast<const bf16x8*>(&Asrc[(wr * 2 + m) * 512 + foff]);
#pragma unroll
      for (int n = 0; n < 4; ++n) bfg[n] = *reinterpret_cast<const bf16x8*>(&Bc[(wc * 4 + n) * 512 + foff]);
      if (p == 0) {
#pragma unroll
        for (int m = 0; m < 2; ++m)
#pragma unroll
          for (int n = 0; n < 4; ++n)
            acc1[m][n] = __builtin_amdgcn_mfma_f32_16x16x32_bf16(af[m], bfg[n], acc1[m][n], 0, 0, 0);
      } else {
#pragma unroll
        for (int m = 0; m < 2; ++m)
#pragma unroll
          for (int n = 0; n < 4; ++n)
            acc2[m][n] = __builtin_amdgcn_mfma_f32_16x16x32_bf16(af[m], bfg[n], acc2[m][n], 0, 0, 0);
      }
      if ((s2 & 7) == 3) {
        const float* fb1p = phA ? fb1a : fb1b;
        float fb[4];
#pragma unroll
        for (int n = 0; n < 4; ++n) fb[n] = fb1p[c * 128 + wc * 64 + n * 16 + (lane & 15)];
#pragma unroll
        for (int m = 0; m < 2; ++m)
#pragma unroll
          for (int n = 0; n < 4; ++n)
#pragma unroll
            for (int j = 0; j < 4; ++j) {
              float t = acc1[m][n][j] + fb[n];
              if (phA) t = 0.5f * t * (1.f + erff(t * 0.70710678118654752f));   // gelu
              else     t = fmaxf(t, 0.f);                                       // relu
              const int r16 = (lane >> 4) * 4 + j;
              const int rb  = wr * 2 + m;
              const int q   = wc * 64 + n * 16 + (lane & 15);
              const int ts2 = q >> 5, ql = q & 31;
              const int s   = (ql >> 3) ^ ((r16 >> 1) & 3);
              Hs[ts2][rb * 512 + r16 * 32 + s * 8 + (ql & 7)] = f2bf(t);
            }
      }
      if (st == 35) {
        // phase-A final epilogue: h2 = acc2 + fb2a + v0(h1) -> As (for GEMM0b); reset accs
        float fb[4];
#pragma unroll
        for (int n = 0; n < 4; ++n) fb[n] = fb2a[colb + n * 16];
        float t[2][4][4];
#pragma unroll
        for (int m = 0; m < 2; ++m)
#pragma unroll
          for (int n = 0; n < 4; ++n)
#pragma unroll
            for (int j = 0; j < 4; ++j)
              t[m][n][j] = acc2[m][n][j] + fb[n] + v0[m][n][j];
        __syncthreads();             // all waves done reading As (last read st=31)
        write_As(t);
#pragma unroll
        for (int m = 0; m < 2; ++m)
#pragma unroll
          for (int n = 0; n < 4; ++n) {
            acc0[m][n] = (f32x4){0.f, 0.f, 0.f, 0.f};
            acc2[m][n] = (f32x4){0.f, 0.f, 0.f, 0.f};
          }
      }
    }
  }

  // ---------- final epilogue: h = LN_n2(acc2 + fb2b + v0(h')) ----------
  float fb[4];
#pragma unroll
  for (int n = 0; n < 4; ++n) fb[n] = fb2b[colb + n * 16];
  float v[2][4][4];
#pragma unroll
  for (int m = 0; m < 2; ++m)
#pragma unroll
    for (int n = 0; n < 4; ++n)
#pragma unroll
      for (int j = 0; j < 4; ++j)
        v[m][n][j] = acc2[m][n][j] + fb[n] + v0[m][n][j];

  ln_tile(v, gC, bC);
#pragma unroll
  for (int m = 0; m < 2; ++m)
#pragma unroll
    for (int n = 0; n < 4; ++n)
#pragma unroll
      for (int j = 0; j < 4; ++j)
        out[(size_t)(rowb + m * 16 + j) * EDIM + colb + n * 16] = f2bf(v[m][n][j]);

  if constexpr (LNM == 2) {
    ln_tile(v, gD, bD);
#pragma unroll
    for (int m = 0; m < 2; ++m)
#pragma unroll
      for (int n = 0; n < 4; ++n)
#pragma unroll
        for (int j = 0; j < 4; ++j)
          outL2[(size_t)(rowb + m * 16 + j) * EDIM + colb + n * 16] = f2bf(v[m][n][j]);
  }
  if constexpr (LNM == 3) {
    const float bc0 = bcp[0];
    float wv[4];
#pragma unroll
    for (int n = 0; n < 4; ++n) wv[n] = Wcp[colb + n * 16];
    float dp[2][4];
#pragma unroll
    for (int m = 0; m < 2; ++m)
#pragma unroll
      for (int j = 0; j < 4; ++j) {
        float s = 0.f;
#pragma unroll
        for (int n = 0; n < 4; ++n) s += v[m][n][j] * wv[n];
        dp[m][j] = s;
      }
#pragma unroll
    for (int o = 1; o < 16; o <<= 1)
#pragma unroll
      for (int m = 0; m < 2; ++m)
#pragma unroll
        for (int j = 0; j < 4; ++j) dp[m][j] += __shfl_xor(dp[m][j], o);
    __syncthreads();
    if ((lane & 15) == 0) {
#pragma unroll
      for (int m = 0; m < 2; ++m)
#pragma unroll
        for (int j = 0; j < 4; ++j)
          lnred[wr][wc][m * 16 + (lane >> 4) * 4 + j][0] = dp[m][j];
    }
    __syncthreads();
    if (wc == 0 && (lane & 15) == 0) {
#pragma unroll
      for (int m = 0; m < 2; ++m)
#pragma unroll
        for (int j = 0; j < 4; ++j) {
          int rloc = m * 16 + (lane >> 4) * 4 + j;
          float t = dp[m][j] + lnred[wr][1][rloc][0] + bc0;
          outCls[n0 + wr * 32 + rloc] = 1.f / (1.f + expf(-t));
        }
    }
  }
}

// ---------------- ctx pass: unstabbed exp sums + dd-max & vsum partials ----------------
__global__ __launch_bounds__(256) void ctxk_kernel(
    const u16* __restrict__ Km, const u16* __restrict__ VT,
    const u16* __restrict__ pjb,
    float* __restrict__ pctx, float* __restrict__ pks,
    float* __restrict__ pvs, float* __restrict__ pmax)
{
  __shared__ __align__(16) u16 kfT[256 * 40];
  __shared__ float wred[4];
  const int tid = threadIdx.x, lane = tid & 63, w = tid >> 6;
  const int h = blockIdx.y, ch = blockIdx.x;
  const int n0 = ch * CR;
  const int g = lane >> 4, c = lane & 15;
  const f32x4 z = (f32x4){0.f, 0.f, 0.f, 0.f};

  bf16x8 pf[4];
#pragma unroll
  for (int jf = 0; jf < 4; ++jf)
    pf[jf] = *reinterpret_cast<const bf16x8*>(pjb + ((w * 4 + jf) * 16 + c) * DHD + g * 8);

  f32x4 cacc[4][2];
#pragma unroll
  for (int mf = 0; mf < 4; ++mf)
#pragma unroll
    for (int df = 0; df < 2; ++df) cacc[mf][df] = z;
  float ksacc[4] = {0.f, 0.f, 0.f, 0.f};
  float lm = -3.4e38f;
  float vs[2] = {0.f, 0.f};

  for (int s = 0; s < CR / 32; ++s) {
    const int rbase = n0 + s * 32;
    bf16x8 af[2];
    float s2[2];
#pragma unroll
    for (int rf = 0; rf < 2; ++rf) {
      af[rf] = *reinterpret_cast<const bf16x8*>(
          Km + (size_t)(rbase + rf * 16 + c) * EDIM + h * DHD + g * 8);
      uint4 ui = *reinterpret_cast<const uint4*>(&af[rf]);
      u32 wd[4] = {ui.x, ui.y, ui.z, ui.w};
      float ss = 0.f;
#pragma unroll
      for (int i = 0; i < 4; ++i) {
        float a = bf2f((u16)(wd[i] & 0xffff)), b = bf2f((u16)(wd[i] >> 16));
        ss += a * a + b * b;
      }
      ss += __shfl_xor(ss, 16); ss += __shfl_xor(ss, 32);
      s2[rf] = ss;
    }
#pragma unroll
    for (int rf = 0; rf < 2; ++rf) {
      float dg[4];
#pragma unroll
      for (int r = 0; r < 4; ++r)
        dg[r] = 0.5f * DN2 * __shfl(s2[rf], (lane & 48) | (4 * g + r));
#pragma unroll
      for (int jf = 0; jf < 4; ++jf) {
        f32x4 d = __builtin_amdgcn_mfma_f32_16x16x32_bf16(af[rf], pf[jf], z, 0, 0, 0);
        lm = fmaxf(lm, fmaxf(fmaxf(d[0], d[1]), fmaxf(d[2], d[3])));
        u16 b0 = f2bf(__expf(d[0] - dg[0]));
        u16 b1 = f2bf(__expf(d[1] - dg[1]));
        u16 b2 = f2bf(__expf(d[2] - dg[2]));
        u16 b3 = f2bf(__expf(d[3] - dg[3]));
        uint2 pk;
        pk.x = (u32)b0 | ((u32)b1 << 16);
        pk.y = (u32)b2 | ((u32)b3 << 16);
        *reinterpret_cast<uint2*>(&kfT[(size_t)(w * 64 + jf * 16 + c) * 40 + rf * 16 + 4 * g]) = pk;
        ksacc[jf] += bf2f(b0) + bf2f(b1) + bf2f(b2) + bf2f(b3);
      }
    }
#pragma unroll
    for (int mf = 0; mf < 4; ++mf) {
      bf16x8 a = *reinterpret_cast<const bf16x8*>(&kfT[(size_t)(w * 64 + mf * 16 + c) * 40 + g * 8]);
#pragma unroll
      for (int df = 0; df < 2; ++df) {
        bf16x8 b = *reinterpret_cast<const bf16x8*>(
            VT + (size_t)(h * DHD + df * 16 + c) * NTOK + rbase + g * 8);
        cacc[mf][df] = __builtin_amdgcn_mfma_f32_16x16x32_bf16(a, b, cacc[mf][df], 0, 0, 0);
      }
    }
    if (w == 0) {
#pragma unroll
      for (int df = 0; df < 2; ++df) {
        bf16x8 b = *reinterpret_cast<const bf16x8*>(
            VT + (size_t)(h * DHD + df * 16 + c) * NTOK + rbase + g * 8);
        uint4 ub = *reinterpret_cast<const uint4*>(&b);
        u32 wd2[4] = {ub.x, ub.y, ub.z, ub.w};
        float sv = 0.f;
#pragma unroll
        for (int i = 0; i < 4; ++i)
          sv += bf2f((u16)(wd2[i] & 0xffff)) + bf2f((u16)(wd2[i] >> 16));
        vs[df] += sv;
      }
    }
  }
#pragma unroll
  for (int jf = 0; jf < 4; ++jf) {
    float vv = ksacc[jf];
    vv += __shfl_xor(vv, 16); vv += __shfl_xor(vv, 32);
    if (g == 0) pks[((size_t)h * NCHK + ch) * MF + w * 64 + jf * 16 + c] = vv;
  }
#pragma unroll
  for (int mf = 0; mf < 4; ++mf)
#pragma unroll
    for (int df = 0; df < 2; ++df)
#pragma unroll
      for (int r = 0; r < 4; ++r) {
        int m = w * 64 + mf * 16 + 4 * g + r;
        int d = df * 16 + c;
        pctx[(((size_t)h * NCHK + ch) * MF + m) * DHD + d] = cacc[mf][df][r];
      }
  if (w == 0) {
#pragma unroll
    for (int df = 0; df < 2; ++df) {
      float v2 = vs[df];
      v2 += __shfl_xor(v2, 16); v2 += __shfl_xor(v2, 32);
      if (g == 0) pvs[((size_t)h * NCHK + ch) * DHD + df * 16 + c] = v2;
    }
  }
#pragma unroll
  for (int o = 1; o < 64; o <<= 1) lm = fmaxf(lm, __shfl_xor(lm, o));
  if (lane == 0) wred[w] = lm;
  __syncthreads();
  if (tid == 0)
    pmax[h * NCHK + ch] = fmaxf(fmaxf(wred[0], wred[1]), fmaxf(wred[2], wred[3]));
}

// ---------------- reduce: global stab + fold exp(-stab)/eps ----------
__global__ __launch_bounds__(256) void reduce_all(
    const float* __restrict__ pctx, const float* __restrict__ pks,
    const float* __restrict__ pvs, const float* __restrict__ pmax,
    u16* __restrict__ ctxT, float* __restrict__ ksg)
{
  __shared__ float red[4];
  const int tid = threadIdx.x;
  float m = fmaxf(pmax[tid], pmax[tid + 256]);
#pragma unroll
  for (int o = 1; o < 64; o <<= 1) m = fmaxf(m, __shfl_xor(m, o));
  if ((tid & 63) == 0) red[tid >> 6] = m;
  __syncthreads();
  const float stab = fmaxf(fmaxf(red[0], red[1]), fmaxf(red[2], red[3]));
  const float esc = __expf(-stab);

  int idx = blockIdx.x * 256 + tid;
  if (idx < HN * MF * DHD) {
    int h = idx >> 13, md = idx & 8191;
    int mm = md >> 5, d = md & 31;
    float s = 0.f, vsum = 0.f;
    for (int c = 0; c < NCHK; ++c) {
      s    += pctx[((size_t)h * NCHK + c) * 8192 + md];
      vsum += pvs[((size_t)h * NCHK + c) * DHD + d];
    }
    ctxT[(size_t)h * 8192 + d * MF + mm] = f2bf(esc * s + KEPS * vsum);
  } else {
    int i2 = idx - HN * MF * DHD;
    if (i2 < HN * MF) {
      int h = i2 >> 8, mm = i2 & 255;
      float s = 0.f;
      for (int c = 0; c < NCHK; ++c) s += pks[((size_t)h * NCHK + c) * MF + mm];
      ksg[i2] = esc * s + KEPS * (float)NTOK;
    }
  }
}

// ---------------- qf + out ----------------
__global__ __launch_bounds__(256) void qout_kernel(
    const u16* __restrict__ Qm, const u16* __restrict__ pjb,
    const u16* __restrict__ ctxT, const float* __restrict__ ksg,
    u16* __restrict__ Am)
{
  __shared__ __align__(16) u16 qfs[4][32 * 40];
  const int tid = threadIdx.x, lane = tid & 63, w = tid >> 6;
  const int h = blockIdx.y;
  const int n0 = blockIdx.x * 128 + w * 32;
  const int g = lane >> 4, c = lane & 15;
  const f32x4 z = (f32x4){0.f, 0.f, 0.f, 0.f};

  bf16x8 af[2];
  float s2[2];
#pragma unroll
  for (int rf = 0; rf < 2; ++rf) {
    af[rf] = *reinterpret_cast<const bf16x8*>(
        Qm + (size_t)(n0 + rf * 16 + c) * EDIM + h * DHD + g * 8);
    uint4 ui = *reinterpret_cast<const uint4*>(&af[rf]);
    u32 wd[4] = {ui.x, ui.y, ui.z, ui.w};
    float ss = 0.f;
#pragma unroll
    for (int i = 0; i < 4; ++i) {
      float a = bf2f((u16)(wd[i] & 0xffff)), b = bf2f((u16)(wd[i] >> 16));
      ss += a * a + b * b;
    }
    ss += __shfl_xor(ss, 16); ss += __shfl_xor(ss, 32);
    s2[rf] = ss;
  }

  float rmax[2][4];
#pragma unroll
  for (int rf = 0; rf < 2; ++rf)
#pragma unroll
    for (int r = 0; r < 4; ++r) rmax[rf][r] = -3.4e38f;
#pragma unroll
  for (int jf = 0; jf < 16; ++jf) {
    bf16x8 b = *reinterpret_cast<const bf16x8*>(pjb + (jf * 16 + c) * DHD + g * 8);
#pragma unroll
    for (int rf = 0; rf < 2; ++rf) {
      f32x4 d = __builtin_amdgcn_mfma_f32_16x16x32_bf16(af[rf], b, z, 0, 0, 0);
#pragma unroll
      for (int r = 0; r < 4; ++r) rmax[rf][r] = fmaxf(rmax[rf][r], d[r]);
    }
  }
#pragma unroll
  for (int rf = 0; rf < 2; ++rf)
#pragma unroll
    for (int r = 0; r < 4; ++r) {
      float vv = rmax[rf][r];
      vv = fmaxf(vv, __shfl_xor(vv, 1)); vv = fmaxf(vv, __shfl_xor(vv, 2));
      vv = fmaxf(vv, __shfl_xor(vv, 4)); vv = fmaxf(vv, __shfl_xor(vv, 8));
      rmax[rf][r] = vv;
    }
  float crow[2][4];
#pragma unroll
  for (int rf = 0; rf < 2; ++rf)
#pragma unroll
    for (int r = 0; r < 4; ++r)
      crow[rf][r] = 0.5f * DN2 * __shfl(s2[rf], (lane & 48) | (4 * g + r)) + rmax[rf][r];

  f32x4 oacc[2][2];
#pragma unroll
  for (int rf = 0; rf < 2; ++rf)
#pragma unroll
    for (int df = 0; df < 2; ++df) oacc[rf][df] = z;
  float Dacc[2][4];
#pragma unroll
  for (int rf = 0; rf < 2; ++rf)
#pragma unroll
    for (int r = 0; r < 4; ++r) Dacc[rf][r] = 0.f;

  for (int ks = 0; ks < 8; ++ks) {
#pragma unroll
    for (int jj = 0; jj < 2; ++jj) {
      const int jf = ks * 2 + jj;
      bf16x8 b = *reinterpret_cast<const bf16x8*>(pjb + (jf * 16 + c) * DHD + g * 8);
      const float ksv = ksg[h * MF + jf * 16 + c];
#pragma unroll
      for (int rf = 0; rf < 2; ++rf) {
        f32x4 d = __builtin_amdgcn_mfma_f32_16x16x32_bf16(af[rf], b, z, 0, 0, 0);
#pragma unroll
        for (int r = 0; r < 4; ++r) {
          float q = __expf(d[r] - crow[rf][r]) + KEPS;
          u16 qb_ = f2bf(q);
          qfs[w][(rf * 16 + 4 * g + r) * 40 + jj * 16 + c] = qb_;
          Dacc[rf][r] += bf2f(qb_) * ksv;
        }
      }
    }
#pragma unroll
    for (int rf = 0; rf < 2; ++rf) {
      bf16x8 a = *reinterpret_cast<const bf16x8*>(&qfs[w][(rf * 16 + c) * 40 + g * 8]);
#pragma unroll
      for (int df = 0; df < 2; ++df) {
        bf16x8 bc = *reinterpret_cast<const bf16x8*>(
            ctxT + (size_t)(h * DHD + df * 16 + c) * MF + ks * 32 + g * 8);
        oacc[rf][df] = __builtin_amdgcn_mfma_f32_16x16x32_bf16(a, bc, oacc[rf][df], 0, 0, 0);
      }
    }
  }
#pragma unroll
  for (int rf = 0; rf < 2; ++rf)
#pragma unroll
    for (int r = 0; r < 4; ++r) {
      float vv = Dacc[rf][r];
      vv += __shfl_xor(vv, 1); vv += __shfl_xor(vv, 2);
      vv += __shfl_xor(vv, 4); vv += __shfl_xor(vv, 8);
      Dacc[rf][r] = vv;
    }
#pragma unroll
  for (int rf = 0; rf < 2; ++rf)
#pragma unroll
    for (int df = 0; df < 2; ++df)
#pragma unroll
      for (int r = 0; r < 4; ++r)
        Am[(size_t)(n0 + rf * 16 + 4 * g + r) * EDIM + h * DHD + df * 16 + c] =
            f2bf(oacc[rf][df][r] / Dacc[rf][r]);
}

// ---------------- host ----------------
extern "C" void kernel_launch(void* const* d_in, const int* in_sizes, int n_in,
                              void* d_out, int out_size, void* d_ws, size_t ws_size,
                              hipStream_t stream)
{
  const float* x    = (const float*)d_in[0];
  const float* Wpin = (const float*)d_in[1];
  const float* bpin = (const float*)d_in[2];
  const float* lag  = (const float*)d_in[3];
  const float* lab  = (const float*)d_in[4];
  const float* Wq   = (const float*)d_in[5];
  const float* Wk   = (const float*)d_in[6];
  const float* Wv   = (const float*)d_in[7];
  const float* Wo   = (const float*)d_in[8];
  const float* bo   = (const float*)d_in[9];
  const float* lbg  = (const float*)d_in[10];
  const float* lbb  = (const float*)d_in[11];
  const float* Wf1  = (const float*)d_in[12];
  const float* bf1  = (const float*)d_in[13];
  const float* Wf2  = (const float*)d_in[14];
  const float* bf2  = (const float*)d_in[15];
  const float* Wpo  = (const float*)d_in[16];
  const float* bpo  = (const float*)d_in[17];
  const float* n1g  = (const float*)d_in[18];
  const float* n1b  = (const float*)d_in[19];
  const float* Wn1  = (const float*)d_in[20];
  const float* bn1  = (const float*)d_in[21];
  const float* Wn2  = (const float*)d_in[22];
  const float* bn2  = (const float*)d_in[23];
  const float* n2g  = (const float*)d_in[24];
  const float* n2b  = (const float*)d_in[25];
  const float* Wc   = (const float*)d_in[26];
  const float* bc   = (const float*)d_in[27];
  const float* proj = (const float*)d_in[28];

  size_t off = 0;
  char* base = (char*)d_ws;
  auto alloc = [&](size_t bytes) -> void* {
    void* p = base + off;
    off += (bytes + 255) & ~(size_t)255;
    return p;
  };
  u16* hb  = (u16*)alloc((size_t)NTOK * EDIM * 2);
  u16* yb  = (u16*)alloc((size_t)NTOK * EDIM * 2);
  u16* qb  = (u16*)alloc((size_t)NTOK * EDIM * 2);
  u16* kb  = (u16*)alloc((size_t)NTOK * EDIM * 2);
  u16* VT  = (u16*)alloc((size_t)HN * DHD * NTOK * 2);
  u16* pjb = (u16*)alloc((size_t)LLAYERS * MF * DHD * 2);
  u16* ctxT = (u16*)alloc((size_t)HN * DHD * MF * 2);
  float* ksg  = (float*)alloc((size_t)HN * MF * 4);
  float* pctx = (float*)alloc((size_t)HN * NCHK * MF * DHD * 4);
  float* pks  = (float*)alloc((size_t)HN * NCHK * MF * 4);
  float* pvs  = (float*)alloc((size_t)HN * NCHK * DHD * 4);
  float* pmax = (float*)alloc((size_t)HN * NCHK * 4);
  u16* wts = (u16*)alloc((size_t)753664 * 2);

  u16* Wpint = wts;
  auto Wqt  = [&](int l){ return wts +  65536 + (size_t)l * 16384; };
  auto Wot  = [&](int l){ return wts + 163840 + (size_t)l * 16384; };
  auto Wpot = [&](int l){ return wts + 196608 + (size_t)l * 16384; };
  auto Wf1t = [&](int l){ return wts + 229376 + (size_t)l * 65536; };
  auto Wf2t = [&](int l){ return wts + 360448 + (size_t)l * 65536; };
  auto Wn1t = [&](int l){ return wts + 491520 + (size_t)l * 65536; };
  auto Wn2t = [&](int l){ return wts + 622592 + (size_t)l * 65536; };

  PrepArgs pa{Wpin, Wq, Wk, Wv, Wo, Wpo, Wf1, Wf2, Wn1, Wn2, proj};
  prep_kernel<<<3008, 256, 0, stream>>>(pa, wts, pjb);

  gemm_in<<<NTOK / 64, 256, 0, stream>>>(x, Wpint, bpin, hb, lag, lab, yb);

  for (int l = 0; l < LLAYERS; ++l) {
    const u16* pjl = pjb + (size_t)l * MF * DHD;

    qkv_f<<<NTOK / 64, 256, 0, stream>>>(yb, Wqt(l), qb, kb, VT);
    ctxk_kernel<<<dim3(NCHK, HN), 256, 0, stream>>>(kb, VT, pjl, pctx, pks, pvs, pmax);
    reduce_all<<<132, 256, 0, stream>>>(pctx, pks, pvs, pmax, ctxT, ksg);
    qout_kernel<<<dim3(NTOK / 128, HN), 256, 0, stream>>>(qb, pjl, ctxT, ksg, yb);

    // mega12: full attn-out + FFN1 + Wpo + FFN2 (one kernel per layer)
    if (l < LLAYERS - 1) {
      mega12<2><<<NTOK / 64, 256, 0, stream>>>(
          yb, hb,
          Wot(l), bo + l * EDIM, lbg + l * EDIM, lbb + l * EDIM,
          Wf1t(l), bf1 + l * FDIM, Wf2t(l), bf2 + l * EDIM,
          Wpot(l), bpo + l * EDIM, n1g + l * EDIM, n1b + l * EDIM,
          Wn1t(l), bn1 + l * FDIM, Wn2t(l), bn2 + l * EDIM,
          n2g + l * EDIM, n2b + l * EDIM,
          hb,
          yb, lag + (l + 1) * EDIM, lab + (l + 1) * EDIM,
          nullptr, nullptr, nullptr);
    } else {
      mega12<3><<<NTOK / 64, 256, 0, stream>>>(
          yb, hb,
          Wot(l), bo + l * EDIM, lbg + l * EDIM, lbb + l * EDIM,
          Wf1t(l), bf1 + l * FDIM, Wf2t(l), bf2 + l * EDIM,
          Wpot(l), bpo + l * EDIM, n1g + l * EDIM, n1b + l * EDIM,
          Wn1t(l), bn1 + l * FDIM, Wn2t(l), bn2 + l * EDIM,
          n2g + l * EDIM, n2b + l * EDIM,
          hb,
          nullptr, nullptr, nullptr,
          Wc, bc, (float*)d_out);
    }
  }
}

// Round 14
// 457.198 us; speedup vs baseline: 6.1931x; 6.1931x over previous
//
#include <hip/hip_runtime.h>
#include <math.h>

// ---------------- problem constants ----------------
#define NTOK  65536
#define EDIM  128
#define HN    4
#define DHD   32
#define MF    256
#define LLAYERS 2
#define INDIM 512
#define FDIM  512
#define CR    512
#define NCHK  (NTOK/CR)

#define DN    0.4204482076268573f
#define DN2   0.17677669529663687f
#define KEPS  1e-4f

typedef unsigned short u16;
typedef unsigned int   u32;
typedef __attribute__((ext_vector_type(8))) __bf16 bf16x8;
typedef __attribute__((ext_vector_type(4))) float  f32x4;

__device__ __forceinline__ u16 f2bf(float f){
  u32 u = __float_as_uint(f);
  u32 r = (u + 0x7fffu + ((u >> 16) & 1u)) >> 16;   // RNE
  return (u16)r;
}
__device__ __forceinline__ float bf2f(u16 h){ return __uint_as_float(((u32)h) << 16); }

__device__ __forceinline__ void gload_lds16(const void* g, void* l){
  __builtin_amdgcn_global_load_lds(
      (const __attribute__((address_space(1))) u32*)g,
      (__attribute__((address_space(3))) u32*)l, 16, 0, 0);
}

// ---------------- prep ----------------
struct PrepArgs {
  const float* Wpin; const float* Wq; const float* Wk; const float* Wv;
  const float* Wo;   const float* Wpo; const float* Wf1; const float* Wf2;
  const float* Wn1;  const float* Wn2; const float* proj;
};

__global__ __launch_bounds__(256) void prep_kernel(PrepArgs a, u16* __restrict__ wts,
                                                   u16* __restrict__ pjb)
{
  int idx = blockIdx.x * 256 + threadIdx.x;
  const float* sp; u16* dp; int r, K, J;
  if      (idx <  65536) { sp = a.Wpin; dp = wts;          r = idx;          K = 512; J = 128; }
  else if (idx <  98304) { sp = a.Wq;   dp = wts +  65536; r = idx -  65536; K = 128; J = 128; }
  else if (idx < 131072) { sp = a.Wk;   dp = wts +  98304; r = idx -  98304; K = 128; J = 128; }
  else if (idx < 163840) { sp = a.Wv;   dp = wts + 131072; r = idx - 131072; K = 128; J = 128; }
  else if (idx < 196608) { sp = a.Wo;   dp = wts + 163840; r = idx - 163840; K = 128; J = 128; }
  else if (idx < 229376) { sp = a.Wpo;  dp = wts + 196608; r = idx - 196608; K = 128; J = 128; }
  else if (idx < 360448) { sp = a.Wf1;  dp = wts + 229376; r = idx - 229376; K = 128; J = 512; }
  else if (idx < 491520) { sp = a.Wf2;  dp = wts + 360448; r = idx - 360448; K = 512; J = 128; }
  else if (idx < 622592) { sp = a.Wn1;  dp = wts + 491520; r = idx - 491520; K = 128; J = 512; }
  else if (idx < 753664) { sp = a.Wn2;  dp = wts + 622592; r = idx - 622592; K = 512; J = 128; }
  else { int p = idx - 753664; pjb[p] = f2bf(a.proj[p] * DN); return; }
  int kj = K * J;
  int l = r / kj, rr = r - l * kj;
  int j = rr / K, k = rr - j * K;
  dp[r] = f2bf(sp[(size_t)l * kj + (size_t)k * J + j]);
}

// ---------------- input GEMM: h = x@Wpin + b (fp32 A), y = LN(h) ----------------
__global__ __launch_bounds__(256, 4) void gemm_in(
    const float* __restrict__ Af, const u16* __restrict__ Bt,
    const float* __restrict__ bias,
    u16* __restrict__ outRaw,
    const float* __restrict__ g1, const float* __restrict__ b1, u16* __restrict__ outL1)
{
  __shared__ __align__(16) u16 Al[3][2048];
  __shared__ __align__(16) u16 Bl[3][4096];
  __shared__ float lnred[2][2][32][2];
  const int tid  = threadIdx.x;
  const int lane = tid & 63;
  const int w    = tid >> 6;
  const int wr   = w >> 1, wc = w & 1;
  const int bid  = blockIdx.x;
  const int bsw  = (bid & 7) * (gridDim.x >> 3) + (bid >> 3);
  const int n0   = bsw * 64;

  f32x4 acc[2][4];
#pragma unroll
  for (int m = 0; m < 2; ++m)
#pragma unroll
    for (int n = 0; n < 4; ++n) acc[m][n] = (f32x4){0.f, 0.f, 0.f, 0.f};

  const int srow = lane >> 2;
  const int skg  = (lane & 3) ^ ((lane >> 3) & 3);

  auto stageB = [&](int buf, int k0) {
#pragma unroll
    for (int i = 0; i < 2; ++i) {
      const int rb = 2 * w + i;
      gload_lds16(Bt + (size_t)(rb * 16 + srow) * 512 + k0 + skg * 8,
                  &Bl[buf][rb * 512]);
    }
  };

  const int r16f = lane & 15;
  const int kgl  = (lane >> 4) ^ ((lane >> 1) & 3);
  const int foff = r16f * 32 + kgl * 8;

  constexpr int T = 16;
  float4 fA[3][2];
  const int r = tid >> 2, hf = tid & 3;
  auto loadA = [&](int slot, int k0) {
    const float* gp = Af + (size_t)(n0 + r) * 512 + k0 + hf * 8;
    fA[slot][0] = ((const float4*)gp)[0];
    fA[slot][1] = ((const float4*)gp)[1];
  };
  const int rbA = r >> 4, r16A = r & 15, swzA = (r16A >> 1) & 3;
  auto writeA = [&](int slot, int buf) {
    uint4 p0;
    p0.x = (u32)f2bf(fA[slot][0].x) | ((u32)f2bf(fA[slot][0].y) << 16);
    p0.y = (u32)f2bf(fA[slot][0].z) | ((u32)f2bf(fA[slot][0].w) << 16);
    p0.z = (u32)f2bf(fA[slot][1].x) | ((u32)f2bf(fA[slot][1].y) << 16);
    p0.w = (u32)f2bf(fA[slot][1].z) | ((u32)f2bf(fA[slot][1].w) << 16);
    *reinterpret_cast<uint4*>(&Al[buf][rbA * 512 + r16A * 32 + (hf ^ swzA) * 8]) = p0;
  };
  loadA(0, 0); loadA(1, 32); loadA(2, 64);
  stageB(0, 0); stageB(1, 32);
  asm volatile("s_waitcnt vmcnt(8)" ::: "memory");
  writeA(0, 0);
#pragma unroll
  for (int t = 0; t < T; ++t) {
    if (t + 2 < T) asm volatile("s_waitcnt vmcnt(4) lgkmcnt(0)" ::: "memory");
    else           asm volatile("s_waitcnt vmcnt(0) lgkmcnt(0)" ::: "memory");
    __builtin_amdgcn_s_barrier();
    if (t + 1 < T) writeA((t + 1) % 3, (t + 1) % 3);
    if (t + 3 < T) loadA((t + 3) % 3, (t + 3) * 32);
    if (t + 2 < T) stageB((t + 2) % 3, (t + 2) * 32);
    {
      const int cur = t % 3;
      bf16x8 af[2], bfg[4];
#pragma unroll
      for (int m = 0; m < 2; ++m)
        af[m]  = *reinterpret_cast<const bf16x8*>(&Al[cur][(wr * 2 + m) * 512 + foff]);
#pragma unroll
      for (int n = 0; n < 4; ++n)
        bfg[n] = *reinterpret_cast<const bf16x8*>(&Bl[cur][(wc * 4 + n) * 512 + foff]);
#pragma unroll
      for (int m = 0; m < 2; ++m)
#pragma unroll
        for (int n = 0; n < 4; ++n)
          acc[m][n] = __builtin_amdgcn_mfma_f32_16x16x32_bf16(af[m], bfg[n], acc[m][n], 0, 0, 0);
    }
  }
  __builtin_amdgcn_s_barrier();

  const int colb = wc * 64 + (lane & 15);
  const int rowb = n0 + wr * 32 + (lane >> 4) * 4;
  float bv[4];
#pragma unroll
  for (int n = 0; n < 4; ++n) bv[n] = bias[colb + n * 16];

  float v[2][4][4];
#pragma unroll
  for (int m = 0; m < 2; ++m)
#pragma unroll
    for (int n = 0; n < 4; ++n)
#pragma unroll
      for (int j = 0; j < 4; ++j)
        v[m][n][j] = acc[m][n][j] + bv[n];

#pragma unroll
  for (int m = 0; m < 2; ++m)
#pragma unroll
    for (int n = 0; n < 4; ++n)
#pragma unroll
      for (int j = 0; j < 4; ++j)
        outRaw[(size_t)(rowb + m * 16 + j) * EDIM + colb + n * 16] = f2bf(v[m][n][j]);

  float rs[2][4], rq[2][4];
#pragma unroll
  for (int m = 0; m < 2; ++m)
#pragma unroll
    for (int j = 0; j < 4; ++j) {
      float s = 0.f, q = 0.f;
#pragma unroll
      for (int n = 0; n < 4; ++n) { float t = v[m][n][j]; s += t; q += t * t; }
      rs[m][j] = s; rq[m][j] = q;
    }
#pragma unroll
  for (int o = 1; o < 16; o <<= 1)
#pragma unroll
    for (int m = 0; m < 2; ++m)
#pragma unroll
      for (int j = 0; j < 4; ++j) {
        rs[m][j] += __shfl_xor(rs[m][j], o);
        rq[m][j] += __shfl_xor(rq[m][j], o);
      }
  __syncthreads();
  if ((lane & 15) == 0) {
#pragma unroll
    for (int m = 0; m < 2; ++m)
#pragma unroll
      for (int j = 0; j < 4; ++j) {
        int rloc = m * 16 + (lane >> 4) * 4 + j;
        lnred[wr][wc][rloc][0] = rs[m][j];
        lnred[wr][wc][rloc][1] = rq[m][j];
      }
  }
  __syncthreads();
  float gg[4], bb[4];
#pragma unroll
  for (int n = 0; n < 4; ++n) { gg[n] = g1[colb + n * 16]; bb[n] = b1[colb + n * 16]; }
#pragma unroll
  for (int m = 0; m < 2; ++m)
#pragma unroll
    for (int j = 0; j < 4; ++j) {
      int rloc = m * 16 + (lane >> 4) * 4 + j;
      float ts = rs[m][j] + lnred[wr][wc ^ 1][rloc][0];
      float tq = rq[m][j] + lnred[wr][wc ^ 1][rloc][1];
      float mu = ts * (1.f / 128.f);
      float rsig = rsqrtf(tq * (1.f / 128.f) - mu * mu + 1e-5f);
#pragma unroll
      for (int n = 0; n < 4; ++n)
        outL1[(size_t)(rowb + m * 16 + j) * EDIM + colb + n * 16] =
            f2bf((v[m][n][j] - mu) * rsig * gg[n] + bb[n]);
    }
}

// ---------------- QKV fused: resident-A, 12 weight stages (q,k,v x 4), 4-deep ----------
__global__ __launch_bounds__(256, 3) void qkv_f(
    const u16* __restrict__ A0, const u16* __restrict__ Wt,
    u16* __restrict__ qout, u16* __restrict__ kout, u16* __restrict__ vtout)
{
  __shared__ __align__(16) u16 As[4][2048];
  __shared__ __align__(16) u16 Bs[4][4096];
  const int tid  = threadIdx.x;
  const int lane = tid & 63;
  const int w    = tid >> 6;
  const int wr   = w >> 1, wc = w & 1;
  const int bid  = blockIdx.x;
  const int bsw  = (bid & 7) * (gridDim.x >> 3) + (bid >> 3);
  const int n0   = bsw * 64;

  const int srow = lane >> 2;
  const int skg  = (lane & 3) ^ ((lane >> 3) & 3);
  const int r16f = lane & 15;
  const int kgl  = (lane >> 4) ^ ((lane >> 1) & 3);
  const int foff = r16f * 32 + kgl * 8;
  const int colb = wc * 64 + (lane & 15);
  const int rowb = n0 + wr * 32 + (lane >> 4) * 4;

#pragma unroll
  for (int rb = 0; rb < 4; ++rb)
    gload_lds16(A0 + (size_t)(n0 + rb * 16 + srow) * EDIM + w * 32 + skg * 8, &As[w][rb * 512]);

  auto stageB = [&](int buf, int st) {
    const u16* base = Wt + (size_t)(st >> 2) * 32768;
    const int kb0 = (st & 3) * 32;
#pragma unroll
    for (int i = 0; i < 2; ++i) {
      const int rb = 2 * w + i;
      gload_lds16(base + (size_t)(rb * 16 + srow) * 128 + kb0 + skg * 8, &Bs[buf][rb * 512]);
    }
  };
  stageB(0, 0); stageB(1, 1); stageB(2, 2);

  f32x4 acc[2][4];
  float v[2][4][4];

#pragma unroll
  for (int st = 0; st < 12; ++st) {
    if (st < 10)       asm volatile("s_waitcnt vmcnt(4) lgkmcnt(0)" ::: "memory");
    else if (st == 10) asm volatile("s_waitcnt vmcnt(2) lgkmcnt(0)" ::: "memory");
    else               asm volatile("s_waitcnt vmcnt(0) lgkmcnt(0)" ::: "memory");
    __builtin_amdgcn_s_barrier();
    if (st + 3 < 12) stageB((st + 3) & 3, st + 3);
    if ((st & 3) == 0) {
#pragma unroll
      for (int m = 0; m < 2; ++m)
#pragma unroll
        for (int n = 0; n < 4; ++n) acc[m][n] = (f32x4){0.f, 0.f, 0.f, 0.f};
    }
    const int kt = st & 3;
    bf16x8 af[2], bfg[4];
#pragma unroll
    for (int m = 0; m < 2; ++m)
      af[m]  = *reinterpret_cast<const bf16x8*>(&As[kt][(wr * 2 + m) * 512 + foff]);
#pragma unroll
    for (int n = 0; n < 4; ++n)
      bfg[n] = *reinterpret_cast<const bf16x8*>(&Bs[st & 3][(wc * 4 + n) * 512 + foff]);
#pragma unroll
    for (int m = 0; m < 2; ++m)
#pragma unroll
      for (int n = 0; n < 4; ++n)
        acc[m][n] = __builtin_amdgcn_mfma_f32_16x16x32_bf16(af[m], bfg[n], acc[m][n], 0, 0, 0);
    if (st == 3 || st == 7) {
      u16* out = (st == 3) ? qout : kout;
#pragma unroll
      for (int m = 0; m < 2; ++m)
#pragma unroll
        for (int n = 0; n < 4; ++n)
#pragma unroll
          for (int j = 0; j < 4; ++j)
            out[(size_t)(rowb + m * 16 + j) * EDIM + colb + n * 16] = f2bf(acc[m][n][j]);
    }
    if (st == 11) {
#pragma unroll
      for (int m = 0; m < 2; ++m)
#pragma unroll
        for (int n = 0; n < 4; ++n)
#pragma unroll
          for (int j = 0; j < 4; ++j) v[m][n][j] = acc[m][n][j];
    }
  }

  __syncthreads();
  u16* tb = &Bs[0][0];   // 128*72*2 = 18KB < 32KB
#pragma unroll
  for (int m = 0; m < 2; ++m)
#pragma unroll
    for (int n = 0; n < 4; ++n)
#pragma unroll
      for (int j = 0; j < 4; ++j)
        tb[(wc * 64 + n * 16 + (lane & 15)) * 72 + wr * 32 + m * 16 + (lane >> 4) * 4 + j]
            = f2bf(v[m][n][j]);
  __syncthreads();
  { const int c2 = tid >> 1, hf2 = tid & 1;
    const uint4* src = reinterpret_cast<const uint4*>(&tb[c2 * 72 + hf2 * 32]);
    uint4* dst = reinterpret_cast<uint4*>(vtout + (size_t)c2 * NTOK + n0 + hf2 * 32);
    dst[0] = src[0]; dst[1] = src[1]; dst[2] = src[2]; dst[3] = src[3]; }
}

// ---------------- MEGA: out = tail( LN0(res0 + A0@W0 + b0) -> FFN ), 4-deep B pipe ----
template<bool RESPOST, int ACT, int LNM>
__global__ __launch_bounds__(256, 2) void mega_f(
    const u16* __restrict__ A0, const u16* __restrict__ W0t,
    const float* __restrict__ b0p, const u16* __restrict__ res0,
    const float* __restrict__ g0, const float* __restrict__ bg0,
    const u16* __restrict__ W1t, const float* __restrict__ fb1p,
    const u16* __restrict__ W2t, const float* __restrict__ fb2p,
    u16* __restrict__ out,
    const float* __restrict__ g1, const float* __restrict__ bt1,
    u16* __restrict__ outL2, const float* __restrict__ g2, const float* __restrict__ bt2,
    const float* __restrict__ Wcp, const float* __restrict__ bcp, float* __restrict__ outCls)
{
  __shared__ __align__(16) u16 As[4][2048];
  __shared__ __align__(16) u16 Hs[4][2048];
  __shared__ __align__(16) u16 Bs[4][4096];
  __shared__ float lnred[2][2][32][2];
  const int tid  = threadIdx.x;
  const int lane = tid & 63;
  const int w    = tid >> 6;
  const int wr   = w >> 1, wc = w & 1;
  const int bid  = blockIdx.x;
  const int bsw  = (bid & 7) * (gridDim.x >> 3) + (bid >> 3);
  const int n0   = bsw * 64;

  const int srow = lane >> 2;
  const int skg  = (lane & 3) ^ ((lane >> 3) & 3);
  const int r16f = lane & 15;
  const int kgl  = (lane >> 4) ^ ((lane >> 1) & 3);
  const int foff = r16f * 32 + kgl * 8;
  const int colb = wc * 64 + (lane & 15);
  const int rowb = n0 + wr * 32 + (lane >> 4) * 4;

#pragma unroll
  for (int rb = 0; rb < 4; ++rb)
    gload_lds16(A0 + (size_t)(n0 + rb * 16 + srow) * EDIM + w * 32 + skg * 8, &As[w][rb * 512]);

  auto stageB = [&](int buf, int st) {
    const u16* base; size_t rstride; int kb0;
    if (st < 4) { base = W0t; rstride = 128; kb0 = st * 32; }
    else {
      int s2 = st - 4;
      int c = s2 >> 3, p = (s2 >> 2) & 1, kt = s2 & 3;
      if (p == 0) { base = W1t + (size_t)c * 16384; rstride = 128; kb0 = kt * 32; }
      else        { base = W2t;                      rstride = 512; kb0 = c * 128 + kt * 32; }
    }
#pragma unroll
    for (int i = 0; i < 2; ++i) {
      const int rb = 2 * w + i;
      gload_lds16(base + (size_t)(rb * 16 + srow) * rstride + kb0 + skg * 8, &Bs[buf][rb * 512]);
    }
  };

  stageB(0, 0); stageB(1, 1); stageB(2, 2);

  f32x4 acc0[2][4], acc1[2][4], acc2[2][4];
#pragma unroll
  for (int m = 0; m < 2; ++m)
#pragma unroll
    for (int n = 0; n < 4; ++n) { acc0[m][n] = (f32x4){0.f,0.f,0.f,0.f}; acc2[m][n] = (f32x4){0.f,0.f,0.f,0.f}; }

  float v0[2][4][4];

#pragma unroll
  for (int st = 0; st < 36; ++st) {
    if (st < 34)       asm volatile("s_waitcnt vmcnt(4) lgkmcnt(0)" ::: "memory");
    else if (st == 34) asm volatile("s_waitcnt vmcnt(2) lgkmcnt(0)" ::: "memory");
    else               asm volatile("s_waitcnt vmcnt(0) lgkmcnt(0)" ::: "memory");
    __builtin_amdgcn_s_barrier();
    if (st + 3 < 36) stageB((st + 3) & 3, st + 3);

    if (st < 4) {
      const u16* Bc = &Bs[st & 3][0];
      bf16x8 af[2], bfg[4];
#pragma unroll
      for (int m = 0; m < 2; ++m) af[m]  = *reinterpret_cast<const bf16x8*>(&As[st][(wr * 2 + m) * 512 + foff]);
#pragma unroll
      for (int n = 0; n < 4; ++n) bfg[n] = *reinterpret_cast<const bf16x8*>(&Bc[(wc * 4 + n) * 512 + foff]);
#pragma unroll
      for (int m = 0; m < 2; ++m)
#pragma unroll
        for (int n = 0; n < 4; ++n)
          acc0[m][n] = __builtin_amdgcn_mfma_f32_16x16x32_bf16(af[m], bfg[n], acc0[m][n], 0, 0, 0);
      if (st == 3) {
        float bv0[4];
#pragma unroll
        for (int n = 0; n < 4; ++n) bv0[n] = b0p[colb + n * 16];
#pragma unroll
        for (int m = 0; m < 2; ++m)
#pragma unroll
          for (int n = 0; n < 4; ++n)
#pragma unroll
            for (int j = 0; j < 4; ++j)
              v0[m][n][j] = acc0[m][n][j] + bv0[n]
                  + bf2f(res0[(size_t)(rowb + m * 16 + j) * EDIM + colb + n * 16]);
        float rs[2][4], rq[2][4];
#pragma unroll
        for (int m = 0; m < 2; ++m)
#pragma unroll
          for (int j = 0; j < 4; ++j) {
            float s = 0.f, q = 0.f;
#pragma unroll
            for (int n = 0; n < 4; ++n) { float t = v0[m][n][j]; s += t; q += t * t; }
            rs[m][j] = s; rq[m][j] = q;
          }
#pragma unroll
        for (int o = 1; o < 16; o <<= 1)
#pragma unroll
          for (int m = 0; m < 2; ++m)
#pragma unroll
            for (int j = 0; j < 4; ++j) {
              rs[m][j] += __shfl_xor(rs[m][j], o);
              rq[m][j] += __shfl_xor(rq[m][j], o);
            }
        __syncthreads();
        if ((lane & 15) == 0) {
#pragma unroll
          for (int m = 0; m < 2; ++m)
#pragma unroll
            for (int j = 0; j < 4; ++j) {
              int rloc = m * 16 + (lane >> 4) * 4 + j;
              lnred[wr][wc][rloc][0] = rs[m][j];
              lnred[wr][wc][rloc][1] = rq[m][j];
            }
        }
        __syncthreads();
        float gg[4], bb[4];
#pragma unroll
        for (int n = 0; n < 4; ++n) { gg[n] = g0[colb + n * 16]; bb[n] = bg0[colb + n * 16]; }
#pragma unroll
        for (int m = 0; m < 2; ++m)
#pragma unroll
          for (int j = 0; j < 4; ++j) {
            int rloc = m * 16 + (lane >> 4) * 4 + j;
            float ts = rs[m][j] + lnred[wr][wc ^ 1][rloc][0];
            float tq = rq[m][j] + lnred[wr][wc ^ 1][rloc][1];
            float mu = ts * (1.f / 128.f);
            float rsig = rsqrtf(tq * (1.f / 128.f) - mu * mu + 1e-5f);
            const int r16 = (lane >> 4) * 4 + j;
            const int rb  = wr * 2 + m;
#pragma unroll
            for (int n = 0; n < 4; ++n) {
              float lnv = (v0[m][n][j] - mu) * rsig * gg[n] + bb[n];
              const int q = wc * 64 + n * 16 + (lane & 15);
              const int ts2 = q >> 5, ql = q & 31;
              const int s = (ql >> 3) ^ ((r16 >> 1) & 3);
              As[ts2][rb * 512 + r16 * 32 + s * 8 + (ql & 7)] = f2bf(lnv);
              if (RESPOST) v0[m][n][j] = lnv;
            }
          }
      }
    } else {
      const int s2 = st - 4;
      const int c = s2 >> 3, p = (s2 >> 2) & 1, kt = s2 & 3;
      if ((s2 & 7) == 0) {
#pragma unroll
        for (int m = 0; m < 2; ++m)
#pragma unroll
          for (int n = 0; n < 4; ++n) acc1[m][n] = (f32x4){0.f, 0.f, 0.f, 0.f};
      }
      const u16* Asrc = p ? &Hs[kt][0] : &As[kt][0];
      const u16* Bc = &Bs[st & 3][0];
      bf16x8 af[2], bfg[4];
#pragma unroll
      for (int m = 0; m < 2; ++m) af[m]  = *reinterpret_cast<const bf16x8*>(&Asrc[(wr * 2 + m) * 512 + foff]);
#pragma unroll
      for (int n = 0; n < 4; ++n) bfg[n] = *reinterpret_cast<const bf16x8*>(&Bc[(wc * 4 + n) * 512 + foff]);
      if (p == 0) {
#pragma unroll
        for (int m = 0; m < 2; ++m)
#pragma unroll
          for (int n = 0; n < 4; ++n)
            acc1[m][n] = __builtin_amdgcn_mfma_f32_16x16x32_bf16(af[m], bfg[n], acc1[m][n], 0, 0, 0);
      } else {
#pragma unroll
        for (int m = 0; m < 2; ++m)
#pragma unroll
          for (int n = 0; n < 4; ++n)
            acc2[m][n] = __builtin_amdgcn_mfma_f32_16x16x32_bf16(af[m], bfg[n], acc2[m][n], 0, 0, 0);
      }
      if ((s2 & 7) == 3) {
        float fb[4];
#pragma unroll
        for (int n = 0; n < 4; ++n) fb[n] = fb1p[c * 128 + wc * 64 + n * 16 + (lane & 15)];
#pragma unroll
        for (int m = 0; m < 2; ++m)
#pragma unroll
          for (int n = 0; n < 4; ++n)
#pragma unroll
            for (int j = 0; j < 4; ++j) {
              float t = acc1[m][n][j] + fb[n];
              if (ACT == 1) t = 0.5f * t * (1.f + erff(t * 0.70710678118654752f));
              else          t = fmaxf(t, 0.f);
              const int r16 = (lane >> 4) * 4 + j;
              const int rb  = wr * 2 + m;
              const int q   = wc * 64 + n * 16 + (lane & 15);
              const int ts2 = q >> 5, ql = q & 31;
              const int s   = (ql >> 3) ^ ((r16 >> 1) & 3);
              Hs[ts2][rb * 512 + r16 * 32 + s * 8 + (ql & 7)] = f2bf(t);
            }
      }
    }
  }

  float fb[4];
#pragma unroll
  for (int n = 0; n < 4; ++n) fb[n] = fb2p[colb + n * 16];
  float v[2][4][4];
#pragma unroll
  for (int m = 0; m < 2; ++m)
#pragma unroll
    for (int n = 0; n < 4; ++n)
#pragma unroll
      for (int j = 0; j < 4; ++j)
        v[m][n][j] = acc2[m][n][j] + fb[n] + v0[m][n][j];

  auto ln_apply = [&](const float* gp, const float* bp) {
    float rs[2][4], rq[2][4];
#pragma unroll
    for (int m = 0; m < 2; ++m)
#pragma unroll
      for (int j = 0; j < 4; ++j) {
        float s = 0.f, q = 0.f;
#pragma unroll
        for (int n = 0; n < 4; ++n) { float t = v[m][n][j]; s += t; q += t * t; }
        rs[m][j] = s; rq[m][j] = q;
      }
#pragma unroll
    for (int o = 1; o < 16; o <<= 1)
#pragma unroll
      for (int m = 0; m < 2; ++m)
#pragma unroll
        for (int j = 0; j < 4; ++j) {
          rs[m][j] += __shfl_xor(rs[m][j], o);
          rq[m][j] += __shfl_xor(rq[m][j], o);
        }
    __syncthreads();
    if ((lane & 15) == 0) {
#pragma unroll
      for (int m = 0; m < 2; ++m)
#pragma unroll
        for (int j = 0; j < 4; ++j) {
          int rloc = m * 16 + (lane >> 4) * 4 + j;
          lnred[wr][wc][rloc][0] = rs[m][j];
          lnred[wr][wc][rloc][1] = rq[m][j];
        }
    }
    __syncthreads();
    float gg[4], bb[4];
#pragma unroll
    for (int n = 0; n < 4; ++n) { gg[n] = gp[colb + n * 16]; bb[n] = bp[colb + n * 16]; }
#pragma unroll
    for (int m = 0; m < 2; ++m)
#pragma unroll
      for (int j = 0; j < 4; ++j) {
        int rloc = m * 16 + (lane >> 4) * 4 + j;
        float ts = rs[m][j] + lnred[wr][wc ^ 1][rloc][0];
        float tq = rq[m][j] + lnred[wr][wc ^ 1][rloc][1];
        float mu = ts * (1.f / 128.f);
        float rsig = rsqrtf(tq * (1.f / 128.f) - mu * mu + 1e-5f);
#pragma unroll
        for (int n = 0; n < 4; ++n)
          v[m][n][j] = (v[m][n][j] - mu) * rsig * gg[n] + bb[n];
      }
  };

  if constexpr (LNM > 0) ln_apply(g1, bt1);
#pragma unroll
  for (int m = 0; m < 2; ++m)
#pragma unroll
    for (int n = 0; n < 4; ++n)
#pragma unroll
      for (int j = 0; j < 4; ++j)
        out[(size_t)(rowb + m * 16 + j) * EDIM + colb + n * 16] = f2bf(v[m][n][j]);

  if constexpr (LNM == 2) {
    ln_apply(g2, bt2);
#pragma unroll
    for (int m = 0; m < 2; ++m)
#pragma unroll
      for (int n = 0; n < 4; ++n)
#pragma unroll
        for (int j = 0; j < 4; ++j)
          outL2[(size_t)(rowb + m * 16 + j) * EDIM + colb + n * 16] = f2bf(v[m][n][j]);
  }
  if constexpr (LNM == 3) {
    const float bc0 = bcp[0];
    float wv[4];
#pragma unroll
    for (int n = 0; n < 4; ++n) wv[n] = Wcp[colb + n * 16];
    float dp[2][4];
#pragma unroll
    for (int m = 0; m < 2; ++m)
#pragma unroll
      for (int j = 0; j < 4; ++j) {
        float s = 0.f;
#pragma unroll
        for (int n = 0; n < 4; ++n) s += v[m][n][j] * wv[n];
        dp[m][j] = s;
      }
#pragma unroll
    for (int o = 1; o < 16; o <<= 1)
#pragma unroll
      for (int m = 0; m < 2; ++m)
#pragma unroll
        for (int j = 0; j < 4; ++j) dp[m][j] += __shfl_xor(dp[m][j], o);
    __syncthreads();
    if ((lane & 15) == 0) {
#pragma unroll
      for (int m = 0; m < 2; ++m)
#pragma unroll
        for (int j = 0; j < 4; ++j)
          lnred[wr][wc][m * 16 + (lane >> 4) * 4 + j][0] = dp[m][j];
    }
    __syncthreads();
    if (wc == 0 && (lane & 15) == 0) {
#pragma unroll
      for (int m = 0; m < 2; ++m)
#pragma unroll
        for (int j = 0; j < 4; ++j) {
          int rloc = m * 16 + (lane >> 4) * 4 + j;
          float t = dp[m][j] + lnred[wr][1][rloc][0] + bc0;
          outCls[n0 + wr * 32 + rloc] = 1.f / (1.f + expf(-t));
        }
    }
  }
}

// ---------------- ctx pass: unstabbed exp sums + dd-max & vsum partials ----------------
__global__ __launch_bounds__(256) void ctxk_kernel(
    const u16* __restrict__ Km, const u16* __restrict__ VT,
    const u16* __restrict__ pjb,
    float* __restrict__ pctx, float* __restrict__ pks,
    float* __restrict__ pvs, float* __restrict__ pmax)
{
  __shared__ __align__(16) u16 kfT[256 * 40];
  __shared__ float wred[4];
  const int tid = threadIdx.x, lane = tid & 63, w = tid >> 6;
  const int h = blockIdx.y, ch = blockIdx.x;
  const int n0 = ch * CR;
  const int g = lane >> 4, c = lane & 15;
  const f32x4 z = (f32x4){0.f, 0.f, 0.f, 0.f};

  bf16x8 pf[4];
#pragma unroll
  for (int jf = 0; jf < 4; ++jf)
    pf[jf] = *reinterpret_cast<const bf16x8*>(pjb + ((w * 4 + jf) * 16 + c) * DHD + g * 8);

  f32x4 cacc[4][2];
#pragma unroll
  for (int mf = 0; mf < 4; ++mf)
#pragma unroll
    for (int df = 0; df < 2; ++df) cacc[mf][df] = z;
  float ksacc[4] = {0.f, 0.f, 0.f, 0.f};
  float lm = -3.4e38f;
  float vs[2] = {0.f, 0.f};

  for (int s = 0; s < CR / 32; ++s) {
    const int rbase = n0 + s * 32;
    bf16x8 af[2];
    float s2[2];
#pragma unroll
    for (int rf = 0; rf < 2; ++rf) {
      af[rf] = *reinterpret_cast<const bf16x8*>(
          Km + (size_t)(rbase + rf * 16 + c) * EDIM + h * DHD + g * 8);
      uint4 ui = *reinterpret_cast<const uint4*>(&af[rf]);
      u32 wd[4] = {ui.x, ui.y, ui.z, ui.w};
      float ss = 0.f;
#pragma unroll
      for (int i = 0; i < 4; ++i) {
        float a = bf2f((u16)(wd[i] & 0xffff)), b = bf2f((u16)(wd[i] >> 16));
        ss += a * a + b * b;
      }
      ss += __shfl_xor(ss, 16); ss += __shfl_xor(ss, 32);
      s2[rf] = ss;
    }
#pragma unroll
    for (int rf = 0; rf < 2; ++rf) {
      float dg[4];
#pragma unroll
      for (int r = 0; r < 4; ++r)
        dg[r] = 0.5f * DN2 * __shfl(s2[rf], (lane & 48) | (4 * g + r));
#pragma unroll
      for (int jf = 0; jf < 4; ++jf) {
        f32x4 d = __builtin_amdgcn_mfma_f32_16x16x32_bf16(af[rf], pf[jf], z, 0, 0, 0);
        lm = fmaxf(lm, fmaxf(fmaxf(d[0], d[1]), fmaxf(d[2], d[3])));
        u16 b0 = f2bf(__expf(d[0] - dg[0]));
        u16 b1 = f2bf(__expf(d[1] - dg[1]));
        u16 b2 = f2bf(__expf(d[2] - dg[2]));
        u16 b3 = f2bf(__expf(d[3] - dg[3]));
        uint2 pk;
        pk.x = (u32)b0 | ((u32)b1 << 16);
        pk.y = (u32)b2 | ((u32)b3 << 16);
        *reinterpret_cast<uint2*>(&kfT[(size_t)(w * 64 + jf * 16 + c) * 40 + rf * 16 + 4 * g]) = pk;
        ksacc[jf] += bf2f(b0) + bf2f(b1) + bf2f(b2) + bf2f(b3);
      }
    }
#pragma unroll
    for (int mf = 0; mf < 4; ++mf) {
      bf16x8 a = *reinterpret_cast<const bf16x8*>(&kfT[(size_t)(w * 64 + mf * 16 + c) * 40 + g * 8]);
#pragma unroll
      for (int df = 0; df < 2; ++df) {
        bf16x8 b = *reinterpret_cast<const bf16x8*>(
            VT + (size_t)(h * DHD + df * 16 + c) * NTOK + rbase + g * 8);
        cacc[mf][df] = __builtin_amdgcn_mfma_f32_16x16x32_bf16(a, b, cacc[mf][df], 0, 0, 0);
      }
    }
    if (w == 0) {
#pragma unroll
      for (int df = 0; df < 2; ++df) {
        bf16x8 b = *reinterpret_cast<const bf16x8*>(
            VT + (size_t)(h * DHD + df * 16 + c) * NTOK + rbase + g * 8);
        uint4 ub = *reinterpret_cast<const uint4*>(&b);
        u32 wd2[4] = {ub.x, ub.y, ub.z, ub.w};
        float sv = 0.f;
#pragma unroll
        for (int i = 0; i < 4; ++i)
          sv += bf2f((u16)(wd2[i] & 0xffff)) + bf2f((u16)(wd2[i] >> 16));
        vs[df] += sv;
      }
    }
  }
#pragma unroll
  for (int jf = 0; jf < 4; ++jf) {
    float vv = ksacc[jf];
    vv += __shfl_xor(vv, 16); vv += __shfl_xor(vv, 32);
    if (g == 0) pks[((size_t)h * NCHK + ch) * MF + w * 64 + jf * 16 + c] = vv;
  }
#pragma unroll
  for (int mf = 0; mf < 4; ++mf)
#pragma unroll
    for (int df = 0; df < 2; ++df)
#pragma unroll
      for (int r = 0; r < 4; ++r) {
        int m = w * 64 + mf * 16 + 4 * g + r;
        int d = df * 16 + c;
        pctx[(((size_t)h * NCHK + ch) * MF + m) * DHD + d] = cacc[mf][df][r];
      }
  if (w == 0) {
#pragma unroll
    for (int df = 0; df < 2; ++df) {
      float v2 = vs[df];
      v2 += __shfl_xor(v2, 16); v2 += __shfl_xor(v2, 32);
      if (g == 0) pvs[((size_t)h * NCHK + ch) * DHD + df * 16 + c] = v2;
    }
  }
#pragma unroll
  for (int o = 1; o < 64; o <<= 1) lm = fmaxf(lm, __shfl_xor(lm, o));
  if (lane == 0) wred[w] = lm;
  __syncthreads();
  if (tid == 0)
    pmax[h * NCHK + ch] = fmaxf(fmaxf(wred[0], wred[1]), fmaxf(wred[2], wred[3]));
}

// ---------------- reduce: global stab + fold exp(-stab)/eps ----------
__global__ __launch_bounds__(256) void reduce_all(
    const float* __restrict__ pctx, const float* __restrict__ pks,
    const float* __restrict__ pvs, const float* __restrict__ pmax,
    u16* __restrict__ ctxT, float* __restrict__ ksg)
{
  __shared__ float red[4];
  const int tid = threadIdx.x;
  float m = fmaxf(pmax[tid], pmax[tid + 256]);
#pragma unroll
  for (int o = 1; o < 64; o <<= 1) m = fmaxf(m, __shfl_xor(m, o));
  if ((tid & 63) == 0) red[tid >> 6] = m;
  __syncthreads();
  const float stab = fmaxf(fmaxf(red[0], red[1]), fmaxf(red[2], red[3]));
  const float esc = __expf(-stab);

  int idx = blockIdx.x * 256 + tid;
  if (idx < HN * MF * DHD) {
    int h = idx >> 13, md = idx & 8191;
    int mm = md >> 5, d = md & 31;
    float s = 0.f, vsum = 0.f;
    for (int c = 0; c < NCHK; ++c) {
      s    += pctx[((size_t)h * NCHK + c) * 8192 + md];
      vsum += pvs[((size_t)h * NCHK + c) * DHD + d];
    }
    ctxT[(size_t)h * 8192 + d * MF + mm] = f2bf(esc * s + KEPS * vsum);
  } else {
    int i2 = idx - HN * MF * DHD;
    if (i2 < HN * MF) {
      int h = i2 >> 8, mm = i2 & 255;
      float s = 0.f;
      for (int c = 0; c < NCHK; ++c) s += pks[((size_t)h * NCHK + c) * MF + mm];
      ksg[i2] = esc * s + KEPS * (float)NTOK;
    }
  }
}

// ---------------- qf + out ----------------
__global__ __launch_bounds__(256) void qout_kernel(
    const u16* __restrict__ Qm, const u16* __restrict__ pjb,
    const u16* __restrict__ ctxT, const float* __restrict__ ksg,
    u16* __restrict__ Am)
{
  __shared__ __align__(16) u16 qfs[4][32 * 40];
  const int tid = threadIdx.x, lane = tid & 63, w = tid >> 6;
  const int h = blockIdx.y;
  const int n0 = blockIdx.x * 128 + w * 32;
  const int g = lane >> 4, c = lane & 15;
  const f32x4 z = (f32x4){0.f, 0.f, 0.f, 0.f};

  bf16x8 af[2];
  float s2[2];
#pragma unroll
  for (int rf = 0; rf < 2; ++rf) {
    af[rf] = *reinterpret_cast<const bf16x8*>(
        Qm + (size_t)(n0 + rf * 16 + c) * EDIM + h * DHD + g * 8);
    uint4 ui = *reinterpret_cast<const uint4*>(&af[rf]);
    u32 wd[4] = {ui.x, ui.y, ui.z, ui.w};
    float ss = 0.f;
#pragma unroll
    for (int i = 0; i < 4; ++i) {
      float a = bf2f((u16)(wd[i] & 0xffff)), b = bf2f((u16)(wd[i] >> 16));
      ss += a * a + b * b;
    }
    ss += __shfl_xor(ss, 16); ss += __shfl_xor(ss, 32);
    s2[rf] = ss;
  }

  float rmax[2][4];
#pragma unroll
  for (int rf = 0; rf < 2; ++rf)
#pragma unroll
    for (int r = 0; r < 4; ++r) rmax[rf][r] = -3.4e38f;
#pragma unroll
  for (int jf = 0; jf < 16; ++jf) {
    bf16x8 b = *reinterpret_cast<const bf16x8*>(pjb + (jf * 16 + c) * DHD + g * 8);
#pragma unroll
    for (int rf = 0; rf < 2; ++rf) {
      f32x4 d = __builtin_amdgcn_mfma_f32_16x16x32_bf16(af[rf], b, z, 0, 0, 0);
#pragma unroll
      for (int r = 0; r < 4; ++r) rmax[rf][r] = fmaxf(rmax[rf][r], d[r]);
    }
  }
#pragma unroll
  for (int rf = 0; rf < 2; ++rf)
#pragma unroll
    for (int r = 0; r < 4; ++r) {
      float vv = rmax[rf][r];
      vv = fmaxf(vv, __shfl_xor(vv, 1)); vv = fmaxf(vv, __shfl_xor(vv, 2));
      vv = fmaxf(vv, __shfl_xor(vv, 4)); vv = fmaxf(vv, __shfl_xor(vv, 8));
      rmax[rf][r] = vv;
    }
  float crow[2][4];
#pragma unroll
  for (int rf = 0; rf < 2; ++rf)
#pragma unroll
    for (int r = 0; r < 4; ++r)
      crow[rf][r] = 0.5f * DN2 * __shfl(s2[rf], (lane & 48) | (4 * g + r)) + rmax[rf][r];

  f32x4 oacc[2][2];
#pragma unroll
  for (int rf = 0; rf < 2; ++rf)
#pragma unroll
    for (int df = 0; df < 2; ++df) oacc[rf][df] = z;
  float Dacc[2][4];
#pragma unroll
  for (int rf = 0; rf < 2; ++rf)
#pragma unroll
    for (int r = 0; r < 4; ++r) Dacc[rf][r] = 0.f;

  for (int ks = 0; ks < 8; ++ks) {
#pragma unroll
    for (int jj = 0; jj < 2; ++jj) {
      const int jf = ks * 2 + jj;
      bf16x8 b = *reinterpret_cast<const bf16x8*>(pjb + (jf * 16 + c) * DHD + g * 8);
      const float ksv = ksg[h * MF + jf * 16 + c];
#pragma unroll
      for (int rf = 0; rf < 2; ++rf) {
        f32x4 d = __builtin_amdgcn_mfma_f32_16x16x32_bf16(af[rf], b, z, 0, 0, 0);
#pragma unroll
        for (int r = 0; r < 4; ++r) {
          float q = __expf(d[r] - crow[rf][r]) + KEPS;
          u16 qb_ = f2bf(q);
          qfs[w][(rf * 16 + 4 * g + r) * 40 + jj * 16 + c] = qb_;
          Dacc[rf][r] += bf2f(qb_) * ksv;
        }
      }
    }
#pragma unroll
    for (int rf = 0; rf < 2; ++rf) {
      bf16x8 a = *reinterpret_cast<const bf16x8*>(&qfs[w][(rf * 16 + c) * 40 + g * 8]);
#pragma unroll
      for (int df = 0; df < 2; ++df) {
        bf16x8 bc = *reinterpret_cast<const bf16x8*>(
            ctxT + (size_t)(h * DHD + df * 16 + c) * MF + ks * 32 + g * 8);
        oacc[rf][df] = __builtin_amdgcn_mfma_f32_16x16x32_bf16(a, bc, oacc[rf][df], 0, 0, 0);
      }
    }
  }
#pragma unroll
  for (int rf = 0; rf < 2; ++rf)
#pragma unroll
    for (int r = 0; r < 4; ++r) {
      float vv = Dacc[rf][r];
      vv += __shfl_xor(vv, 1); vv += __shfl_xor(vv, 2);
      vv += __shfl_xor(vv, 4); vv += __shfl_xor(vv, 8);
      Dacc[rf][r] = vv;
    }
#pragma unroll
  for (int rf = 0; rf < 2; ++rf)
#pragma unroll
    for (int df = 0; df < 2; ++df)
#pragma unroll
      for (int r = 0; r < 4; ++r)
        Am[(size_t)(n0 + rf * 16 + 4 * g + r) * EDIM + h * DHD + df * 16 + c] =
            f2bf(oacc[rf][df][r] / Dacc[rf][r]);
}

// ---------------- host ----------------
extern "C" void kernel_launch(void* const* d_in, const int* in_sizes, int n_in,
                              void* d_out, int out_size, void* d_ws, size_t ws_size,
                              hipStream_t stream)
{
  const float* x    = (const float*)d_in[0];
  const float* Wpin = (const float*)d_in[1];
  const float* bpin = (const float*)d_in[2];
  const float* lag  = (const float*)d_in[3];
  const float* lab  = (const float*)d_in[4];
  const float* Wq   = (const float*)d_in[5];
  const float* Wk   = (const float*)d_in[6];
  const float* Wv   = (const float*)d_in[7];
  const float* Wo   = (const float*)d_in[8];
  const float* bo   = (const float*)d_in[9];
  const float* lbg  = (const float*)d_in[10];
  const float* lbb  = (const float*)d_in[11];
  const float* Wf1  = (const float*)d_in[12];
  const float* bf1  = (const float*)d_in[13];
  const float* Wf2  = (const float*)d_in[14];
  const float* bf2  = (const float*)d_in[15];
  const float* Wpo  = (const float*)d_in[16];
  const float* bpo  = (const float*)d_in[17];
  const float* n1g  = (const float*)d_in[18];
  const float* n1b  = (const float*)d_in[19];
  const float* Wn1  = (const float*)d_in[20];
  const float* bn1  = (const float*)d_in[21];
  const float* Wn2  = (const float*)d_in[22];
  const float* bn2  = (const float*)d_in[23];
  const float* n2g  = (const float*)d_in[24];
  const float* n2b  = (const float*)d_in[25];
  const float* Wc   = (const float*)d_in[26];
  const float* bc   = (const float*)d_in[27];
  const float* proj = (const float*)d_in[28];

  size_t off = 0;
  char* base = (char*)d_ws;
  auto alloc = [&](size_t bytes) -> void* {
    void* p = base + off;
    off += (bytes + 255) & ~(size_t)255;
    return p;
  };
  u16* hb  = (u16*)alloc((size_t)NTOK * EDIM * 2);
  u16* yb  = (u16*)alloc((size_t)NTOK * EDIM * 2);
  u16* qb  = (u16*)alloc((size_t)NTOK * EDIM * 2);
  u16* kb  = (u16*)alloc((size_t)NTOK * EDIM * 2);
  u16* vb  = (u16*)alloc((size_t)NTOK * EDIM * 2);
  u16* VT  = (u16*)alloc((size_t)HN * DHD * NTOK * 2);
  u16* pjb = (u16*)alloc((size_t)LLAYERS * MF * DHD * 2);
  u16* ctxT = (u16*)alloc((size_t)HN * DHD * MF * 2);
  float* ksg  = (float*)alloc((size_t)HN * MF * 4);
  float* pctx = (float*)alloc((size_t)HN * NCHK * MF * DHD * 4);
  float* pks  = (float*)alloc((size_t)HN * NCHK * MF * 4);
  float* pvs  = (float*)alloc((size_t)HN * NCHK * DHD * 4);
  float* pmax = (float*)alloc((size_t)HN * NCHK * 4);
  u16* wts = (u16*)alloc((size_t)753664 * 2);

  u16* Wpint = wts;
  auto Wqt  = [&](int l){ return wts +  65536 + (size_t)l * 16384; };
  auto Wot  = [&](int l){ return wts + 163840 + (size_t)l * 16384; };
  auto Wpot = [&](int l){ return wts + 196608 + (size_t)l * 16384; };
  auto Wf1t = [&](int l){ return wts + 229376 + (size_t)l * 65536; };
  auto Wf2t = [&](int l){ return wts + 360448 + (size_t)l * 65536; };
  auto Wn1t = [&](int l){ return wts + 491520 + (size_t)l * 65536; };
  auto Wn2t = [&](int l){ return wts + 622592 + (size_t)l * 65536; };

  PrepArgs pa{Wpin, Wq, Wk, Wv, Wo, Wpo, Wf1, Wf2, Wn1, Wn2, proj};
  prep_kernel<<<3008, 256, 0, stream>>>(pa, wts, pjb);

  gemm_in<<<NTOK / 64, 256, 0, stream>>>(x, Wpint, bpin, hb, lag, lab, yb);

  for (int l = 0; l < LLAYERS; ++l) {
    const u16* pjl = pjb + (size_t)l * MF * DHD;

    qkv_f<<<NTOK / 64, 256, 0, stream>>>(yb, Wqt(l), qb, kb, VT);
    ctxk_kernel<<<dim3(NCHK, HN), 256, 0, stream>>>(kb, VT, pjl, pctx, pks, pvs, pmax);
    reduce_all<<<132, 256, 0, stream>>>(pctx, pks, pvs, pmax, ctxT, ksg);
    qout_kernel<<<dim3(NTOK / 128, HN), 256, 0, stream>>>(qb, pjl, ctxT, ksg, yb);

    mega_f<false, 1, 0><<<NTOK / 64, 256, 0, stream>>>(
        yb, Wot(l), bo + l * EDIM, hb, lbg + l * EDIM, lbb + l * EDIM,
        Wf1t(l), bf1 + l * FDIM, Wf2t(l), bf2 + l * EDIM, vb,
        nullptr, nullptr, nullptr, nullptr, nullptr, nullptr, nullptr, nullptr);

    if (l < LLAYERS - 1) {
      mega_f<true, 2, 2><<<NTOK / 64, 256, 0, stream>>>(
          vb, Wpot(l), bpo + l * EDIM, hb, n1g + l * EDIM, n1b + l * EDIM,
          Wn1t(l), bn1 + l * FDIM, Wn2t(l), bn2 + l * EDIM, hb,
          n2g + l * EDIM, n2b + l * EDIM,
          yb, lag + (l + 1) * EDIM, lab + (l + 1) * EDIM,
          nullptr, nullptr, nullptr);
    } else {
      mega_f<true, 2, 3><<<NTOK / 64, 256, 0, stream>>>(
          vb, Wpot(l), bpo + l * EDIM, hb, n1g + l * EDIM, n1b + l * EDIM,
          Wn1t(l), bn1 + l * FDIM, Wn2t(l), bn2 + l * EDIM, hb,
          n2g + l * EDIM, n2b + l * EDIM,
          nullptr, nullptr, nullptr,
          Wc, bc, (float*)d_out);
    }
  }
}